// Round 6
// baseline (794.397 us; speedup 1.0000x reference)
//
#include <hip/hip_runtime.h>
#include <stdint.h>

#define NN 50000
#define EE 800000
#define FIN 256
#define HD 128
#define DD 32
#define KK 25000
#define SLOPEF 0.4f
#define NEGF (-1e9f)
#define ATT_OFF 34
#define STR_OFF (34 + EE * 4)
#define CW 128             // LDS-cached edges per node (deg ~Poisson(16); recompute fallback)

// ---------- helpers ----------
__device__ __forceinline__ unsigned fkey(float x) {
    unsigned u = __float_as_uint(x);
    return (u & 0x80000000u) ? ~u : (u | 0x80000000u);   // monotone float->uint
}
__device__ __forceinline__ float unfkey(unsigned k) {
    unsigned u = (k & 0x80000000u) ? (k ^ 0x80000000u) : ~k;
    return __uint_as_float(u);
}
__device__ __forceinline__ float lrelu(float v) { return v > 0.f ? v : SLOPEF * v; }

// ---------- pointer bundle ----------
struct P {
    // inputs
    const float *feature, *strength, *W0, *b0, *al0, *ar0, *Wc0, *bc0;
    const float *W1, *b1, *al1, *ar1, *gW, *gb, *cW, *cb;
    const int *src, *dst;
    // zeroed scratch
    double *Zacc, *racc;
    int *deg_i, *deg_o, *cur0, *deg1, *cur1, *cnt;
    unsigned *gmaxk, *rs;         // rs[0]=pivot key, rs[1]=ties needed, rs[2]=hi bin, rs[3]=hi remaining
    unsigned *binsHi, *binsLo;
    // other scratch
    unsigned *keys;
    int *csr_src, *off0, *off1, *sel, *slot, *list;
    float *z0, *x, *el0, *er0, *hc, *score, *z1;
    float *el1, *er1, *m1f, *s1f, *res, *g, *tscale;
    float *out;                    // d_out (float32)
};

// ---------- fp32 tiled GEMM: C[M,128] = A[M,Kd] @ B[Kd,128] ----------
// 128x64 tile, 8x4 acc/thread. GATHER: A-row = x[list[gr]] * tscale[gr] (kills k_xk).
// ELR: epilogue computes el/er for this block's 2 heads from acc regs (kills k_elr).
#define BM 128
#define BN 64
#define BK 16
template <bool GATHER, bool ELR>
__global__ __launch_bounds__(256) void k_gemm(
    const float* __restrict__ A, const float* __restrict__ B, float* __restrict__ C,
    int M, int Kd,
    const int* __restrict__ list, const float* __restrict__ tscale,
    const float* __restrict__ al, const float* __restrict__ ar,
    float* __restrict__ el, float* __restrict__ er) {
    __shared__ float As[BK][BM + 4];
    __shared__ float Bs[BK][BN];
    int bm = blockIdx.y * BM, bn = blockIdx.x * BN;
    int tid = threadIdx.x;
    int tr = tid >> 4, tc = tid & 15;
    int lrow = tid >> 1;                       // staging row (2 threads/row)
    int arow = -1; float asc = 1.f;
    {
        int gr = bm + lrow;
        if (gr < M) {
            if (GATHER) { arow = list[gr]; asc = tscale[gr]; }
            else arow = gr;
        }
    }
    float acc[8][4] = {};
    for (int k0 = 0; k0 < Kd; k0 += BK) {
        {
            int col = (tid & 1) << 3;
            float4 v0 = {0.f,0.f,0.f,0.f}, v1 = {0.f,0.f,0.f,0.f};
            if (arow >= 0) {
                const float* ap = A + (size_t)arow * Kd + k0 + col;
                v0 = *(const float4*)ap; v1 = *(const float4*)(ap + 4);
                if (GATHER) {
                    v0.x *= asc; v0.y *= asc; v0.z *= asc; v0.w *= asc;
                    v1.x *= asc; v1.y *= asc; v1.z *= asc; v1.w *= asc;
                }
            }
            As[col + 0][lrow] = v0.x; As[col + 1][lrow] = v0.y;
            As[col + 2][lrow] = v0.z; As[col + 3][lrow] = v0.w;
            As[col + 4][lrow] = v1.x; As[col + 5][lrow] = v1.y;
            As[col + 6][lrow] = v1.z; As[col + 7][lrow] = v1.w;
        }
        {
            int kr = tid >> 4, col = (tid & 15) << 2;
            float4 v = *(const float4*)(B + (size_t)(k0 + kr) * HD + bn + col);
            *(float4*)&Bs[kr][col] = v;
        }
        __syncthreads();
#pragma unroll
        for (int kk = 0; kk < BK; kk++) {
            float a[8], b[4];
#pragma unroll
            for (int i = 0; i < 8; i++) a[i] = As[kk][tr * 8 + i];
#pragma unroll
            for (int j = 0; j < 4; j++) b[j] = Bs[kk][tc * 4 + j];
#pragma unroll
            for (int i = 0; i < 8; i++)
#pragma unroll
                for (int j = 0; j < 4; j++) acc[i][j] = fmaf(a[i], b[j], acc[i][j]);
        }
        __syncthreads();
    }
#pragma unroll
    for (int i = 0; i < 8; i++) {
        int gr = bm + tr * 8 + i;
        if (gr < M) {
            float4 v = {acc[i][0], acc[i][1], acc[i][2], acc[i][3]};
            *(float4*)(C + (size_t)gr * HD + bn + tc * 4) = v;
        }
    }
    if (ELR) {
        // this block's 64 channels = heads 2*bx, 2*bx+1; 8-lane tree reduce per (row, head)
        int head = blockIdx.x * 2 + (tc >> 3);
        int dbase = (tc & 7) * 4;
        const float* alh = al + head * 32 + dbase;
        const float* arh = ar + head * 32 + dbase;
        float a0 = alh[0], a1 = alh[1], a2 = alh[2], a3 = alh[3];
        float r0 = arh[0], r1 = arh[1], r2 = arh[2], r3 = arh[3];
#pragma unroll
        for (int i = 0; i < 8; i++) {
            int gr = bm + tr * 8 + i;
            float pe = acc[i][0]*a0 + acc[i][1]*a1 + acc[i][2]*a2 + acc[i][3]*a3;
            float pr = acc[i][0]*r0 + acc[i][1]*r1 + acc[i][2]*r2 + acc[i][3]*r3;
#pragma unroll
            for (int o = 1; o < 8; o <<= 1) { pe += __shfl_xor(pe, o); pr += __shfl_xor(pr, o); }
            if ((tc & 7) == 0 && gr < M) { el[gr * 4 + head] = pe; er[gr * 4 + head] = pr; }
        }
    }
}

// ---------- degrees ----------
__global__ void k_deg(P p) {
    int e = blockIdx.x * blockDim.x + threadIdx.x;
    if (e >= EE) return;
    atomicAdd(&p.deg_i[p.dst[e]], 1);
    atomicAdd(&p.deg_o[p.src[e]], 1);
}

// ---------- exclusive scan (single block 1024, wave shfl-scan) ----------
__global__ __launch_bounds__(1024) void k_scan(const int* __restrict__ deg, int* __restrict__ off, int n) {
    __shared__ int ws[16];
    __shared__ int woff[17];
    int t = threadIdx.x;
    int per = (n + 1023) / 1024;
    int s0 = t * per; if (s0 > n) s0 = n;
    int e0 = s0 + per; if (e0 > n) e0 = n;
    int s = 0;
    for (int i = s0; i < e0; i++) s += deg[i];
    int lane = t & 63, w = t >> 6;
    int val = s;
    for (int o = 1; o < 64; o <<= 1) { int u = __shfl_up(val, o); if (lane >= o) val += u; }
    if (lane == 63) ws[w] = val;
    __syncthreads();
    if (t == 0) { int a = 0; for (int i = 0; i < 16; i++) { woff[i] = a; a += ws[i]; } woff[16] = a; }
    __syncthreads();
    if (t == 0) off[n] = woff[16];
    int acc = woff[w] + val - s;   // exclusive prefix
    for (int i = s0; i < e0; i++) { off[i] = acc; acc += deg[i]; }
}

// ---------- CSR scatter (src-ids only) ----------
__global__ void k_scatter0(P p) {
    int e = blockIdx.x * blockDim.x + threadIdx.x;
    if (e >= EE) return;
    int d = p.dst[e];
    int pos = p.off0[d] + atomicAdd(&p.cur0[d], 1);
    p.csr_src[pos] = p.src[e];
}

// ---------- FUSED GAT aggregate: wave-per-node ----------
// 4 nodes/block (N,K divisible by 4 -> no tail). Softmax: lane = head*16+sub,
// all 64 lanes busy at deg~16; 16-lane shfl_xor butterflies; m/s broadcast via
// __shfl. Phase 3: lane handles channels (lane, lane+64); SGPR row base via
// readfirstlane. One __syncthreads (sexp/ssrc cross-lane handoff).
template <int EPI>
__global__ __launch_bounds__(256) void k_fgat(
    const int* __restrict__ off, const int* __restrict__ csrs,
    const float* __restrict__ el, const float* __restrict__ er,
    const float* __restrict__ z, const float* __restrict__ bias,
    float* __restrict__ xout, float* __restrict__ mf, float* __restrict__ sf,
    const float* __restrict__ Wc, const int* __restrict__ dego, float* __restrict__ hc,
    const float* __restrict__ gW, const float* __restrict__ gb,
    float* __restrict__ res, float* __restrict__ g) {
    __shared__ int ssrc[4][CW];
    __shared__ float sexp[4][CW][4];
    int wv = threadIdx.x >> 6, lane = threadIdx.x & 63;
    int v = blockIdx.x * 4 + wv;
    int b = off[v], e = off[v + 1], deg = e - b;
    int h = lane >> 4, sub = lane & 15;
    float4 er4 = *(const float4*)(er + (size_t)v * 4);
    float erh = ((const float*)&er4)[h];
    // phase 1: per-head max (16 lanes per head)
    float m = NEGF;
    for (int li = sub; li < deg; li += 16) {
        int s = csrs[b + li];
        if (h == 0 && li < CW) ssrc[wv][li] = s;
        m = fmaxf(m, lrelu(el[(size_t)s * 4 + h] + erh));
    }
#pragma unroll
    for (int o = 1; o < 16; o <<= 1) m = fmaxf(m, __shfl_xor(m, o));
    // phase 2: exp + sum
    float ssum = 0.f;
    for (int li = sub; li < deg; li += 16) {
        int s = csrs[b + li];
        float x = expf(lrelu(el[(size_t)s * 4 + h] + erh) - m);
        if (li < CW) sexp[wv][li][h] = x;
        ssum += x;
    }
#pragma unroll
    for (int o = 1; o < 16; o <<= 1) ssum += __shfl_xor(ssum, o);
    __syncthreads();
    // phase 3: channel-parallel weighted gather, 2 channels/lane
    int h0 = lane >> 5, h1 = h0 + 2;
    float m0 = __shfl(m, h0 << 4), m1 = __shfl(m, h1 << 4);
    float s0 = __shfl(ssum, h0 << 4), s1 = __shfl(ssum, h1 << 4);
    int c0 = lane, c1 = lane + 64;
    float acc0 = 0.f, acc1 = 0.f;
    for (int li = 0; li < deg; li++) {
        int s; float w0, w1;
        if (li < CW) {
            s = ssrc[wv][li];
            w0 = sexp[wv][li][h0]; w1 = sexp[wv][li][h1];
        } else {
            s = csrs[b + li];
            w0 = expf(lrelu(el[(size_t)s * 4 + h0] + ((const float*)&er4)[h0]) - m0);
            w1 = expf(lrelu(el[(size_t)s * 4 + h1] + ((const float*)&er4)[h1]) - m1);
        }
        int su = __builtin_amdgcn_readfirstlane(s);
        const float* zr = z + (size_t)su * HD;
        acc0 = fmaf(w0, zr[c0], acc0);
        acc1 = fmaf(w1, zr[c1], acc1);
    }
    float xc0 = acc0 / fmaxf(s0, 1e-16f) + bias[c0];
    float xc1 = acc1 / fmaxf(s1, 1e-16f) + bias[c1];
    if (EPI == 1) {
        float* xr = xout + (size_t)v * HD;
        xr[c0] = xc0; xr[c1] = xc1;
        float pc = xc0 * Wc[c0] + xc1 * Wc[c1];
#pragma unroll
        for (int o = 1; o < 64; o <<= 1) pc += __shfl_xor(pc, o);
        if (lane == 0) hc[v] = pc / sqrtf(fmaxf((float)dego[v], 1.f));
    }
    if (EPI == 2) {
        float mbc = __shfl(m, (lane & 3) << 4);
        float sbc = __shfl(ssum, (lane & 3) << 4);
        if (lane < 4) { mf[v * 4 + lane] = mbc; sf[v * 4 + lane] = sbc; }
        float t = xc0 + xc1;              // x[c]+x[c+64]
        t += __shfl_xor(t, 32);           // + x[c+32]+x[c+96]
        float pg = 0.f;
        if (lane < 32) {
            float r = 0.25f * t;
            res[(size_t)v * 32 + lane] = r;
            pg = r * gW[lane];
        }
#pragma unroll
        for (int o = 1; o < 32; o <<= 1) pg += __shfl_xor(pg, o);
        if (lane == 0) g[v] = pg + gb[0];
    }
}

// ---------- SAGPool score ----------
__global__ void k_score(P p) {
    int v = blockIdx.x * blockDim.x + threadIdx.x;
    if (v >= NN) return;
    int b = p.off0[v], en = p.off0[v + 1];
    float acc = 0.f;
    for (int i = b; i < en; i++) acc += p.hc[p.csr_src[i]];
    float dg = fmaxf((float)(en - b), 1.f);
    float sc = acc / sqrtf(dg) + p.bc0[0];
    p.score[v] = sc;
    p.keys[v] = fkey(sc);
}

// ---------- radix select: 2 x 16-bit passes (was 4 x 8-bit) ----------
__global__ void k_hist2(P p, int level) {
    int v = blockIdx.x * blockDim.x + threadIdx.x;
    if (v >= NN) return;
    unsigned key = p.keys[v];
    if (level == 0) atomicAdd(&p.binsHi[key >> 16], 1u);
    else if ((key >> 16) == p.rs[2]) atomicAdd(&p.binsLo[key & 0xFFFFu], 1u);
}
__global__ __launch_bounds__(1024) void k_rsel2(P p, int level) {
    const unsigned* bins = level ? p.binsLo : p.binsHi;
    int K = level ? (int)p.rs[3] : KK;
    __shared__ unsigned wsm[16];
    __shared__ unsigned wpre[17];
    int t = threadIdx.x;
    unsigned base = (unsigned)t * 64;
    unsigned S = 0;
    for (int i = 0; i < 64; i++) S += bins[base + i];
    int lane = t & 63, w = t >> 6;
    unsigned val = S;
    for (int o = 1; o < 64; o <<= 1) { unsigned u = __shfl_up(val, o); if (lane >= o) val += u; }
    if (lane == 63) wsm[w] = val;
    __syncthreads();
    if (t == 0) { unsigned a = 0; for (int i = 0; i < 16; i++) { wpre[i] = a; a += wsm[i]; } wpre[16] = a; }
    __syncthreads();
    unsigned incl = wpre[w] + val;
    unsigned running = wpre[16] - incl;    // count of keys in strictly higher bins
    for (int i = 63; i >= 0; i--) {
        unsigned c = bins[base + i];
        unsigned above = running;
        running += c;
        if ((int)above < K && (int)running >= K) {
            if (level == 0) { p.rs[2] = base + (unsigned)i; p.rs[3] = (unsigned)(K - (int)above); }
            else { p.rs[0] = (p.rs[2] << 16) | (base + (unsigned)i); p.rs[1] = (unsigned)(K - (int)above); }
        }
    }
}
__global__ void k_sel(P p) {
    int v = blockIdx.x * blockDim.x + threadIdx.x;
    if (v >= NN) return;
    p.sel[v] = (p.keys[v] > p.rs[0]) ? 1 : 0;
}
__global__ __launch_bounds__(1024) void k_ties(P p) {   // lowest-index ties (matches top_k)
    __shared__ int base;
    __shared__ int wsums[16];
    unsigned pivot = p.rs[0];
    int need = (int)p.rs[1];
    if (threadIdx.x == 0) base = 0;
    __syncthreads();
    for (int st = 0; st < NN; st += 1024) {
        int v = st + (int)threadIdx.x;
        int flag = (v < NN && p.keys[v] == pivot) ? 1 : 0;
        unsigned long long m = __ballot(flag);
        int lane = threadIdx.x & 63, w = threadIdx.x >> 6;
        int pre = __popcll(m & ((1ull << lane) - 1ull));
        if (lane == 0) wsums[w] = __popcll(m);
        __syncthreads();
        int woff = 0;
        for (int i = 0; i < w; i++) woff += wsums[i];
        int rank = base + woff + pre;
        if (flag && rank < need) p.sel[v] = 1;
        __syncthreads();
        if (threadIdx.x == 0) {
            int s = 0;
            for (int i = 0; i < 16; i++) s += wsums[i];
            base += s;
        }
        __syncthreads();
    }
}
__global__ void k_list(P p) {
    int v = blockIdx.x * blockDim.x + threadIdx.x;
    if (v >= NN) return;
    if (p.sel[v]) {
        int i = atomicAdd(p.cnt, 1);
        p.list[i] = v;
        p.slot[v] = i;
        p.tscale[i] = tanhf(p.score[v]);
    } else {
        p.slot[v] = -1;
    }
}

// ---------- layer-1 graph (valid edges only, slot-indexed) ----------
__global__ void k_deg1(P p) {
    int e = blockIdx.x * blockDim.x + threadIdx.x;
    if (e >= EE) return;
    int ds = p.slot[p.src[e]], dd = p.slot[p.dst[e]];
    if (ds >= 0 && dd >= 0) atomicAdd(&p.deg1[dd], 1);
}
__global__ void k_scatter1(P p) {
    int e = blockIdx.x * blockDim.x + threadIdx.x;
    if (e >= EE) return;
    int ds = p.slot[p.src[e]], dd = p.slot[p.dst[e]];
    if (ds >= 0 && dd >= 0) {
        int pos = p.off1[dd] + atomicAdd(&p.cur1[dd], 1);
        p.csr_src[pos] = ds;
    }
}
// per-edge alpha outputs: pure reads, writes atten+strength for ALL edges
__global__ void k_ealpha1(P p) {
    int e = blockIdx.x * blockDim.x + threadIdx.x;
    if (e >= EE) return;
    int ds = p.slot[p.src[e]], dd = p.slot[p.dst[e]];
    float a[4] = {0.f, 0.f, 0.f, 0.f};
    float st = 0.f;
    if (ds >= 0 && dd >= 0) {
        float4 es = *(const float4*)(p.el1 + ds * 4);
        float4 ed = *(const float4*)(p.er1 + dd * 4);
        float l[4] = {lrelu(es.x + ed.x), lrelu(es.y + ed.y), lrelu(es.z + ed.z), lrelu(es.w + ed.w)};
#pragma unroll
        for (int h = 0; h < 4; h++) {
            float m = p.m1f[dd * 4 + h];
            float ex = expf(l[h] - m);
            a[h] = ex / fmaxf(p.s1f[dd * 4 + h], 1e-16f);
        }
        st = p.strength[e];
    }
    float* o = p.out + ATT_OFF + (size_t)e * 4;
    *(float2*)(o) = make_float2(a[0], a[1]);
    *(float2*)(o + 2) = make_float2(a[2], a[3]);
    p.out[STR_OFF + e] = st;
}

// ---------- readout ----------
__global__ void k_gmax(P p) {
    __shared__ float red[256];
    int t = threadIdx.x;
    float m = -3.4e38f;
    for (int i = blockIdx.x * 256 + t; i < KK; i += gridDim.x * 256) m = fmaxf(m, p.g[i]);
    red[t] = m;
    __syncthreads();
    for (int o = 128; o > 0; o >>= 1) { if (t < o) red[t] = fmaxf(red[t], red[t + o]); __syncthreads(); }
    if (t == 0) atomicMax(p.gmaxk, fkey(red[0]));   // memset-0 identity ok
}
#define WSUM_BLOCKS 104
__global__ __launch_bounds__(256) void k_wsum(P p) {
    __shared__ double vred[256];
    __shared__ double zred[8];
    int t = threadIdx.x, il = t >> 5, d = t & 31;
    float gm = unfkey(*p.gmaxk);
    double accv = 0.0, accw = 0.0;
    for (int i = blockIdx.x * 8 + il; i < KK; i += WSUM_BLOCKS * 8) {
        float w = expf(p.g[i] - gm);
        accv += (double)(w * p.res[(size_t)i * 32 + d]);
        if (d == 0) accw += (double)w;
    }
    vred[t] = accv;
    if (d == 0) zred[il] = accw;
    __syncthreads();
    if (il == 0) {
        double s = 0;
#pragma unroll
        for (int k2 = 0; k2 < 8; k2++) s += vred[k2 * 32 + d];
        atomicAdd(&p.racc[d], s);
    }
    if (t == 32) {
        double z2 = 0;
#pragma unroll
        for (int k2 = 0; k2 < 8; k2++) z2 += zred[k2];
        atomicAdd(p.Zacc, z2);
    }
}
__global__ void k_final(P p) {
    __shared__ float rb[32];
    int t = threadIdx.x;
    double Z = *p.Zacc;
    if (t < 32) {
        float r = (float)(p.racc[t] / Z);
        p.out[t] = r;
        rb[t] = r;
    }
    __syncthreads();
    if (t < 2) {
        float s = 0.f;
        for (int d = 0; d < 32; d++) s += rb[d] * p.cW[d * 2 + t];
        p.out[32 + t] = s + p.cb[t];
    }
}

// ---------- host ----------
extern "C" void kernel_launch(void* const* d_in, const int* in_sizes, int n_in,
                              void* d_out, int out_size, void* d_ws, size_t ws_size,
                              hipStream_t stream) {
    (void)in_sizes; (void)n_in; (void)out_size; (void)ws_size;
    P p;
    p.feature  = (const float*)d_in[0];
    p.strength = (const float*)d_in[1];
    p.W0  = (const float*)d_in[2];  p.b0  = (const float*)d_in[3];
    p.al0 = (const float*)d_in[4];  p.ar0 = (const float*)d_in[5];
    p.Wc0 = (const float*)d_in[6];  p.bc0 = (const float*)d_in[7];
    p.W1  = (const float*)d_in[8];  p.b1  = (const float*)d_in[9];
    p.al1 = (const float*)d_in[10]; p.ar1 = (const float*)d_in[11];
    p.gW  = (const float*)d_in[12]; p.gb  = (const float*)d_in[13];
    p.cW  = (const float*)d_in[14]; p.cb  = (const float*)d_in[15];
    p.src = (const int*)d_in[16];   p.dst = (const int*)d_in[17];
    p.out = (float*)d_out;

    char* ws = (char*)d_ws;
    size_t off = 0;
    auto alloc = [&](size_t bytes) -> void* {
        void* r = ws + off;
        off = (off + bytes + 255) & ~(size_t)255;
        return r;
    };
    // ---- zeroed region (must stay first/contiguous) ----
    p.Zacc  = (double*)alloc(8);
    p.racc  = (double*)alloc(32 * 8);
    p.deg_i = (int*)alloc((size_t)NN * 4);
    p.deg_o = (int*)alloc((size_t)NN * 4);
    p.cur0  = (int*)alloc((size_t)NN * 4);
    p.deg1  = (int*)alloc((size_t)KK * 4);
    p.cur1  = (int*)alloc((size_t)KK * 4);
    p.cnt   = (int*)alloc(4);
    p.gmaxk = (unsigned*)alloc(4);
    p.rs    = (unsigned*)alloc(16);
    p.binsHi = (unsigned*)alloc(65536 * 4);
    p.binsLo = (unsigned*)alloc(65536 * 4);
    size_t zbytes = off;
    // ---- big buffers ----
    p.z0 = (float*)alloc((size_t)NN * HD * 4);
    p.x  = (float*)alloc((size_t)NN * HD * 4);
    p.z1 = (float*)alloc((size_t)KK * HD * 4);   // separate: gemm1 gathers from x while writing z1
    p.csr_src = (int*)alloc((size_t)EE * 4);
    p.el0 = (float*)alloc((size_t)NN * 4 * 4);
    p.er0 = (float*)alloc((size_t)NN * 4 * 4);
    p.off0 = (int*)alloc((size_t)(NN + 1) * 4);
    p.off1 = (int*)alloc((size_t)(KK + 1) * 4);
    p.hc    = (float*)alloc((size_t)NN * 4);
    p.score = (float*)alloc((size_t)NN * 4);
    p.keys  = (unsigned*)alloc((size_t)NN * 4);
    p.sel   = (int*)alloc((size_t)NN * 4);
    p.slot  = (int*)alloc((size_t)NN * 4);
    p.list  = (int*)alloc((size_t)KK * 4);
    p.tscale = (float*)alloc((size_t)KK * 4);
    p.el1 = (float*)alloc((size_t)KK * 4 * 4);
    p.er1 = (float*)alloc((size_t)KK * 4 * 4);
    p.m1f = (float*)alloc((size_t)KK * 4 * 4);
    p.s1f = (float*)alloc((size_t)KK * 4 * 4);
    p.res = (float*)alloc((size_t)KK * DD * 4);
    p.g   = (float*)alloc((size_t)KK * 4);

    const int GB_E = (EE + 255) / 256;        // 3125
    const int GB_N = (NN + 255) / 256;        // 196

    hipMemsetAsync(d_ws, 0, zbytes, stream);

    // ---- GAT layer 0 ----
    k_gemm<false, true><<<dim3(2, (NN + BM - 1) / BM), 256, 0, stream>>>(
        p.feature, p.W0, p.z0, NN, FIN, nullptr, nullptr, p.al0, p.ar0, p.el0, p.er0);
    k_deg<<<GB_E, 256, 0, stream>>>(p);
    k_scan<<<1, 1024, 0, stream>>>(p.deg_i, p.off0, NN);
    k_scatter0<<<GB_E, 256, 0, stream>>>(p);
    k_fgat<1><<<NN / 4, 256, 0, stream>>>(p.off0, p.csr_src, p.el0, p.er0, p.z0, p.b0,
                                          p.x, nullptr, nullptr,
                                          p.Wc0, p.deg_o, p.hc,
                                          nullptr, nullptr, nullptr, nullptr);

    // ---- SAGPool ----
    k_score<<<GB_N, 256, 0, stream>>>(p);
    k_hist2<<<GB_N, 256, 0, stream>>>(p, 0);
    k_rsel2<<<1, 1024, 0, stream>>>(p, 0);
    k_hist2<<<GB_N, 256, 0, stream>>>(p, 1);
    k_rsel2<<<1, 1024, 0, stream>>>(p, 1);
    k_sel<<<GB_N, 256, 0, stream>>>(p);
    k_ties<<<1, 1024, 0, stream>>>(p);
    k_list<<<GB_N, 256, 0, stream>>>(p);

    // ---- GAT layer 1 ----
    k_gemm<true, true><<<dim3(2, (KK + BM - 1) / BM), 256, 0, stream>>>(
        p.x, p.W1, p.z1, KK, HD, p.list, p.tscale, p.al1, p.ar1, p.el1, p.er1);
    k_deg1<<<GB_E, 256, 0, stream>>>(p);
    k_scan<<<1, 1024, 0, stream>>>(p.deg1, p.off1, KK);
    k_scatter1<<<GB_E, 256, 0, stream>>>(p);
    k_fgat<2><<<KK / 4, 256, 0, stream>>>(p.off1, p.csr_src, p.el1, p.er1, p.z1, p.b1,
                                          nullptr, p.m1f, p.s1f,
                                          nullptr, nullptr, nullptr,
                                          p.gW, p.gb, p.res, p.g);
    k_ealpha1<<<GB_E, 256, 0, stream>>>(p);

    // ---- readout ----
    k_gmax<<<98, 256, 0, stream>>>(p);
    k_wsum<<<WSUM_BLOCKS, 256, 0, stream>>>(p);
    k_final<<<1, 64, 0, stream>>>(p);
}

// Round 7
// 747.404 us; speedup vs baseline: 1.0629x; 1.0629x over previous
//
#include <hip/hip_runtime.h>
#include <stdint.h>

#define NN 50000
#define EE 800000
#define FIN 256
#define HD 128
#define DD 32
#define KK 25000
#define SLOPEF 0.4f
#define NEGF (-1e9f)
#define ATT_OFF 34
#define STR_OFF (34 + EE * 4)
#define CW 128             // LDS-cached edges per node (deg ~Poisson(16); recompute fallback)

// ---------- helpers ----------
__device__ __forceinline__ unsigned fkey(float x) {
    unsigned u = __float_as_uint(x);
    return (u & 0x80000000u) ? ~u : (u | 0x80000000u);   // monotone float->uint
}
__device__ __forceinline__ float unfkey(unsigned k) {
    unsigned u = (k & 0x80000000u) ? (k ^ 0x80000000u) : ~k;
    return __uint_as_float(u);
}
__device__ __forceinline__ float lrelu(float v) { return v > 0.f ? v : SLOPEF * v; }

// ---------- pointer bundle ----------
struct P {
    // inputs
    const float *feature, *strength, *W0, *b0, *al0, *ar0, *Wc0, *bc0;
    const float *W1, *b1, *al1, *ar1, *gW, *gb, *cW, *cb;
    const int *src, *dst;
    // zeroed scratch
    double *Zacc, *racc;
    int *deg_i, *deg_o, *cur0, *deg1, *cur1, *cnt;
    unsigned *gmaxk, *rs;         // rs[0]=pivot key, rs[1]=ties needed, rs[2]=hi bin, rs[3]=hi remaining
    unsigned *binsHi, *binsLo;
    // other scratch
    unsigned *keys;
    int *csr_src, *off0, *off1, *sel, *slot, *list;
    float *z0, *el0, *er0, *q4, *m0f, *s0f, *b0wc, *hc, *score, *xk, *z1;
    float *el1, *er1, *m1f, *s1f, *res, *g, *tscale;
    float *out;                    // d_out (float32)
};

// ---------- fp32 tiled GEMM: C[M,128] = A[M,Kd] @ B[Kd,128] ----------
// ELR epilogue: el/er for this block's 2 heads from acc regs; optional q4
// (per-head z.Wc chunks) for the SAGPool scalar-score path.
#define BM 128
#define BN 64
#define BK 16
__global__ __launch_bounds__(256) void k_gemm(
    const float* __restrict__ A, const float* __restrict__ B, float* __restrict__ C,
    int M, int Kd,
    const float* __restrict__ al, const float* __restrict__ ar,
    float* __restrict__ el, float* __restrict__ er,
    const float* __restrict__ Wc, float* __restrict__ q4) {
    __shared__ float As[BK][BM + 4];
    __shared__ float Bs[BK][BN];
    int bm = blockIdx.y * BM, bn = blockIdx.x * BN;
    int tid = threadIdx.x;
    int tr = tid >> 4, tc = tid & 15;
    int lrow = tid >> 1;
    int arow = (bm + lrow < M) ? (bm + lrow) : -1;
    float acc[8][4] = {};
    for (int k0 = 0; k0 < Kd; k0 += BK) {
        {
            int col = (tid & 1) << 3;
            float4 v0 = {0.f,0.f,0.f,0.f}, v1 = {0.f,0.f,0.f,0.f};
            if (arow >= 0) {
                const float* ap = A + (size_t)arow * Kd + k0 + col;
                v0 = *(const float4*)ap; v1 = *(const float4*)(ap + 4);
            }
            As[col + 0][lrow] = v0.x; As[col + 1][lrow] = v0.y;
            As[col + 2][lrow] = v0.z; As[col + 3][lrow] = v0.w;
            As[col + 4][lrow] = v1.x; As[col + 5][lrow] = v1.y;
            As[col + 6][lrow] = v1.z; As[col + 7][lrow] = v1.w;
        }
        {
            int kr = tid >> 4, col = (tid & 15) << 2;
            float4 v = *(const float4*)(B + (size_t)(k0 + kr) * HD + bn + col);
            *(float4*)&Bs[kr][col] = v;
        }
        __syncthreads();
#pragma unroll
        for (int kk = 0; kk < BK; kk++) {
            float a[8], b[4];
#pragma unroll
            for (int i = 0; i < 8; i++) a[i] = As[kk][tr * 8 + i];
#pragma unroll
            for (int j = 0; j < 4; j++) b[j] = Bs[kk][tc * 4 + j];
#pragma unroll
            for (int i = 0; i < 8; i++)
#pragma unroll
                for (int j = 0; j < 4; j++) acc[i][j] = fmaf(a[i], b[j], acc[i][j]);
        }
        __syncthreads();
    }
#pragma unroll
    for (int i = 0; i < 8; i++) {
        int gr = bm + tr * 8 + i;
        if (gr < M) {
            float4 v = {acc[i][0], acc[i][1], acc[i][2], acc[i][3]};
            *(float4*)(C + (size_t)gr * HD + bn + tc * 4) = v;
        }
    }
    // epilogue: heads 2*bx, 2*bx+1; 8-lane tree reduce per (row, head)
    int head = blockIdx.x * 2 + (tc >> 3);
    int dbase = (tc & 7) * 4;
    const float* alh = al + head * 32 + dbase;
    const float* arh = ar + head * 32 + dbase;
    float a0 = alh[0], a1 = alh[1], a2 = alh[2], a3 = alh[3];
    float r0 = arh[0], r1 = arh[1], r2 = arh[2], r3 = arh[3];
    float w0 = 0.f, w1 = 0.f, w2 = 0.f, w3 = 0.f;
    if (Wc) {
        const float* wch = Wc + head * 32 + dbase;
        w0 = wch[0]; w1 = wch[1]; w2 = wch[2]; w3 = wch[3];
    }
#pragma unroll
    for (int i = 0; i < 8; i++) {
        int gr = bm + tr * 8 + i;
        float pe = acc[i][0]*a0 + acc[i][1]*a1 + acc[i][2]*a2 + acc[i][3]*a3;
        float pr = acc[i][0]*r0 + acc[i][1]*r1 + acc[i][2]*r2 + acc[i][3]*r3;
        float pq = acc[i][0]*w0 + acc[i][1]*w1 + acc[i][2]*w2 + acc[i][3]*w3;
#pragma unroll
        for (int o = 1; o < 8; o <<= 1) {
            pe += __shfl_xor(pe, o); pr += __shfl_xor(pr, o); pq += __shfl_xor(pq, o);
        }
        if ((tc & 7) == 0 && gr < M) {
            el[gr * 4 + head] = pe; er[gr * 4 + head] = pr;
            if (Wc) q4[gr * 4 + head] = pq;
        }
    }
}

// ---------- b0.Wc0 scalar ----------
__global__ void k_prep(const float* __restrict__ b0, const float* __restrict__ Wc,
                       float* __restrict__ b0wc) {
    int l = threadIdx.x;
    float t = b0[l] * Wc[l] + b0[l + 64] * Wc[l + 64];
#pragma unroll
    for (int o = 1; o < 64; o <<= 1) t += __shfl_xor(t, o);
    if (l == 0) b0wc[0] = t;
}

// ---------- degrees ----------
__global__ void k_deg(P p) {
    int e = blockIdx.x * blockDim.x + threadIdx.x;
    if (e >= EE) return;
    atomicAdd(&p.deg_i[p.dst[e]], 1);
    atomicAdd(&p.deg_o[p.src[e]], 1);
}

// ---------- exclusive scan (single block 1024, wave shfl-scan) ----------
__global__ __launch_bounds__(1024) void k_scan(const int* __restrict__ deg, int* __restrict__ off, int n) {
    __shared__ int ws[16];
    __shared__ int woff[17];
    int t = threadIdx.x;
    int per = (n + 1023) / 1024;
    int s0 = t * per; if (s0 > n) s0 = n;
    int e0 = s0 + per; if (e0 > n) e0 = n;
    int s = 0;
    for (int i = s0; i < e0; i++) s += deg[i];
    int lane = t & 63, w = t >> 6;
    int val = s;
    for (int o = 1; o < 64; o <<= 1) { int u = __shfl_up(val, o); if (lane >= o) val += u; }
    if (lane == 63) ws[w] = val;
    __syncthreads();
    if (t == 0) { int a = 0; for (int i = 0; i < 16; i++) { woff[i] = a; a += ws[i]; } woff[16] = a; }
    __syncthreads();
    if (t == 0) off[n] = woff[16];
    int acc = woff[w] + val - s;
    for (int i = s0; i < e0; i++) { off[i] = acc; acc += deg[i]; }
}

// ---------- CSR scatter (src-ids only) ----------
__global__ void k_scatter0(P p) {
    int e = blockIdx.x * blockDim.x + threadIdx.x;
    if (e >= EE) return;
    int d = p.dst[e];
    int pos = p.off0[d] + atomicAdd(&p.cur0[d], 1);
    p.csr_src[pos] = p.src[e];
}

// ---------- layer-0 softmax + SCALAR q-gather (all nodes) ----------
// x.Wc0 = sum_h (sum_j exp_j q_h[s_j])/s_h + b0.Wc0 -> per-edge reads are 8 B
// from L2-resident el0/q4 (1.6 MB) instead of 512 B z-rows. Saves m,s for k_fgatx.
__global__ __launch_bounds__(256) void k_fgatlite(
    const int* __restrict__ off, const int* __restrict__ csrs,
    const float* __restrict__ el, const float* __restrict__ er,
    const float* __restrict__ q4, const int* __restrict__ dego,
    const float* __restrict__ b0wc,
    float* __restrict__ hc, float* __restrict__ m0f, float* __restrict__ s0f) {
    int wv = threadIdx.x >> 6, lane = threadIdx.x & 63;
    int v = blockIdx.x * 4 + wv;
    int b = off[v], e = off[v + 1], deg = e - b;
    int h = lane >> 4, sub = lane & 15;
    float erh = er[(size_t)v * 4 + h];
    float m = NEGF;
    for (int li = sub; li < deg; li += 16) {
        int s = csrs[b + li];
        m = fmaxf(m, lrelu(el[(size_t)s * 4 + h] + erh));
    }
#pragma unroll
    for (int o = 1; o < 16; o <<= 1) m = fmaxf(m, __shfl_xor(m, o));
    float ssum = 0.f, hq = 0.f;
    for (int li = sub; li < deg; li += 16) {
        int s = csrs[b + li];
        float ex = expf(lrelu(el[(size_t)s * 4 + h] + erh) - m);
        ssum += ex;
        hq = fmaf(ex, q4[(size_t)s * 4 + h], hq);
    }
#pragma unroll
    for (int o = 1; o < 16; o <<= 1) { ssum += __shfl_xor(ssum, o); hq += __shfl_xor(hq, o); }
    if (sub == 0) { m0f[v * 4 + h] = m; s0f[v * 4 + h] = ssum; }
    float t = hq / fmaxf(ssum, 1e-16f);     // uniform within head group
    t += __shfl_xor(t, 16);
    t += __shfl_xor(t, 32);                 // sum over 4 heads
    if (lane == 0)
        hc[v] = (t + b0wc[0]) / sqrtf(fmaxf((float)dego[v], 1.f));
}

// ---------- full x for SELECTED nodes only: xk[i] = (GAT0 out + b0)*tanh ----------
// m,s reused from fgatlite; ~400k edges touch z-rows (half of layer-0 total).
__global__ __launch_bounds__(256) void k_fgatx(
    const int* __restrict__ list, const float* __restrict__ tscale,
    const int* __restrict__ off, const int* __restrict__ csrs,
    const float* __restrict__ el, const float* __restrict__ er,
    const float* __restrict__ m0f, const float* __restrict__ s0f,
    const float* __restrict__ z, const float* __restrict__ b0,
    float* __restrict__ xk) {
    __shared__ int ssrc[4][CW];
    __shared__ float sexp[4][CW][4];
    int wv = threadIdx.x >> 6, lane = threadIdx.x & 63;
    int i = blockIdx.x * 4 + wv;
    int v = list[i];
    int b = off[v], e = off[v + 1], deg = e - b;
    int h = lane >> 4, sub = lane & 15;
    float erh = er[(size_t)v * 4 + h];
    float mh = m0f[v * 4 + h];
    for (int li = sub; li < deg; li += 16) {
        int s = csrs[b + li];
        if (h == 0 && li < CW) ssrc[wv][li] = s;
        if (li < CW) sexp[wv][li][h] = expf(lrelu(el[(size_t)s * 4 + h] + erh) - mh);
    }
    __syncthreads();
    int h0 = lane >> 5, h1 = h0 + 2;
    float s0 = s0f[v * 4 + h0], s1 = s0f[v * 4 + h1];
    float m0 = m0f[v * 4 + h0], m1 = m0f[v * 4 + h1];
    float er0v = er[(size_t)v * 4 + h0], er1v = er[(size_t)v * 4 + h1];
    int c0 = lane, c1 = lane + 64;
    float acc0 = 0.f, acc1 = 0.f;
    for (int li = 0; li < deg; li++) {
        int s; float w0, w1;
        if (li < CW) {
            s = ssrc[wv][li];
            w0 = sexp[wv][li][h0]; w1 = sexp[wv][li][h1];
        } else {
            s = csrs[b + li];
            w0 = expf(lrelu(el[(size_t)s * 4 + h0] + er0v) - m0);
            w1 = expf(lrelu(el[(size_t)s * 4 + h1] + er1v) - m1);
        }
        int su = __builtin_amdgcn_readfirstlane(s);
        const float* zr = z + (size_t)su * HD;
        acc0 = fmaf(w0, zr[c0], acc0);
        acc1 = fmaf(w1, zr[c1], acc1);
    }
    float ts = tscale[i];
    float* xr = xk + (size_t)i * HD;
    xr[c0] = (acc0 / fmaxf(s0, 1e-16f) + b0[c0]) * ts;
    xr[c1] = (acc1 / fmaxf(s1, 1e-16f) + b0[c1]) * ts;
}

// ---------- SAGPool score ----------
__global__ void k_score(P p) {
    int v = blockIdx.x * blockDim.x + threadIdx.x;
    if (v >= NN) return;
    int b = p.off0[v], en = p.off0[v + 1];
    float acc = 0.f;
    for (int i = b; i < en; i++) acc += p.hc[p.csr_src[i]];
    float dg = fmaxf((float)(en - b), 1.f);
    float sc = acc / sqrtf(dg) + p.bc0[0];
    p.score[v] = sc;
    p.keys[v] = fkey(sc);
}

// ---------- radix select: 2 x 16-bit passes ----------
__global__ void k_hist2(P p, int level) {
    int v = blockIdx.x * blockDim.x + threadIdx.x;
    if (v >= NN) return;
    unsigned key = p.keys[v];
    if (level == 0) atomicAdd(&p.binsHi[key >> 16], 1u);
    else if ((key >> 16) == p.rs[2]) atomicAdd(&p.binsLo[key & 0xFFFFu], 1u);
}
__global__ __launch_bounds__(1024) void k_rsel2(P p, int level) {
    const unsigned* bins = level ? p.binsLo : p.binsHi;
    int K = level ? (int)p.rs[3] : KK;
    __shared__ unsigned wsm[16];
    __shared__ unsigned wpre[17];
    int t = threadIdx.x;
    unsigned base = (unsigned)t * 64;
    unsigned S = 0;
    for (int i = 0; i < 64; i++) S += bins[base + i];
    int lane = t & 63, w = t >> 6;
    unsigned val = S;
    for (int o = 1; o < 64; o <<= 1) { unsigned u = __shfl_up(val, o); if (lane >= o) val += u; }
    if (lane == 63) wsm[w] = val;
    __syncthreads();
    if (t == 0) { unsigned a = 0; for (int i = 0; i < 16; i++) { wpre[i] = a; a += wsm[i]; } wpre[16] = a; }
    __syncthreads();
    unsigned incl = wpre[w] + val;
    unsigned running = wpre[16] - incl;    // keys in strictly higher bins
    for (int i = 63; i >= 0; i--) {
        unsigned c = bins[base + i];
        unsigned above = running;
        running += c;
        if ((int)above < K && (int)running >= K) {
            if (level == 0) { p.rs[2] = base + (unsigned)i; p.rs[3] = (unsigned)(K - (int)above); }
            else { p.rs[0] = (p.rs[2] << 16) | (base + (unsigned)i); p.rs[1] = (unsigned)(K - (int)above); }
        }
    }
}
__global__ void k_sel(P p) {
    int v = blockIdx.x * blockDim.x + threadIdx.x;
    if (v >= NN) return;
    p.sel[v] = (p.keys[v] > p.rs[0]) ? 1 : 0;
}
__global__ __launch_bounds__(1024) void k_ties(P p) {   // lowest-index ties (matches top_k)
    __shared__ int base;
    __shared__ int wsums[16];
    unsigned pivot = p.rs[0];
    int need = (int)p.rs[1];
    if (threadIdx.x == 0) base = 0;
    __syncthreads();
    for (int st = 0; st < NN; st += 1024) {
        int v = st + (int)threadIdx.x;
        int flag = (v < NN && p.keys[v] == pivot) ? 1 : 0;
        unsigned long long m = __ballot(flag);
        int lane = threadIdx.x & 63, w = threadIdx.x >> 6;
        int pre = __popcll(m & ((1ull << lane) - 1ull));
        if (lane == 0) wsums[w] = __popcll(m);
        __syncthreads();
        int woff = 0;
        for (int i = 0; i < w; i++) woff += wsums[i];
        int rank = base + woff + pre;
        if (flag && rank < need) p.sel[v] = 1;
        __syncthreads();
        if (threadIdx.x == 0) {
            int s = 0;
            for (int i = 0; i < 16; i++) s += wsums[i];
            base += s;
        }
        __syncthreads();
    }
}
__global__ void k_list(P p) {
    int v = blockIdx.x * blockDim.x + threadIdx.x;
    if (v >= NN) return;
    if (p.sel[v]) {
        int i = atomicAdd(p.cnt, 1);
        p.list[i] = v;
        p.slot[v] = i;
        p.tscale[i] = tanhf(p.score[v]);
    } else {
        p.slot[v] = -1;
    }
}

// ---------- layer-1 graph (valid edges only, slot-indexed) ----------
__global__ void k_deg1(P p) {
    int e = blockIdx.x * blockDim.x + threadIdx.x;
    if (e >= EE) return;
    int ds = p.slot[p.src[e]], dd = p.slot[p.dst[e]];
    if (ds >= 0 && dd >= 0) atomicAdd(&p.deg1[dd], 1);
}
__global__ void k_scatter1(P p) {
    int e = blockIdx.x * blockDim.x + threadIdx.x;
    if (e >= EE) return;
    int ds = p.slot[p.src[e]], dd = p.slot[p.dst[e]];
    if (ds >= 0 && dd >= 0) {
        int pos = p.off1[dd] + atomicAdd(&p.cur1[dd], 1);
        p.csr_src[pos] = ds;
    }
}

// ---------- layer-1 fused GAT (wave-per-node) + res/g epilogue ----------
__global__ __launch_bounds__(256) void k_fgat2(
    const int* __restrict__ off, const int* __restrict__ csrs,
    const float* __restrict__ el, const float* __restrict__ er,
    const float* __restrict__ z, const float* __restrict__ bias,
    float* __restrict__ mf, float* __restrict__ sf,
    const float* __restrict__ gW, const float* __restrict__ gb,
    float* __restrict__ res, float* __restrict__ g) {
    __shared__ int ssrc[4][CW];
    __shared__ float sexp[4][CW][4];
    int wv = threadIdx.x >> 6, lane = threadIdx.x & 63;
    int v = blockIdx.x * 4 + wv;
    int b = off[v], e = off[v + 1], deg = e - b;
    int h = lane >> 4, sub = lane & 15;
    float4 er4 = *(const float4*)(er + (size_t)v * 4);
    float erh = ((const float*)&er4)[h];
    float m = NEGF;
    for (int li = sub; li < deg; li += 16) {
        int s = csrs[b + li];
        if (h == 0 && li < CW) ssrc[wv][li] = s;
        m = fmaxf(m, lrelu(el[(size_t)s * 4 + h] + erh));
    }
#pragma unroll
    for (int o = 1; o < 16; o <<= 1) m = fmaxf(m, __shfl_xor(m, o));
    float ssum = 0.f;
    for (int li = sub; li < deg; li += 16) {
        int s = csrs[b + li];
        float x = expf(lrelu(el[(size_t)s * 4 + h] + erh) - m);
        if (li < CW) sexp[wv][li][h] = x;
        ssum += x;
    }
#pragma unroll
    for (int o = 1; o < 16; o <<= 1) ssum += __shfl_xor(ssum, o);
    if (sub == 0) { mf[v * 4 + h] = m; sf[v * 4 + h] = ssum; }
    __syncthreads();
    int h0 = lane >> 5, h1 = h0 + 2;
    float m0 = __shfl(m, h0 << 4), m1 = __shfl(m, h1 << 4);
    float s0 = __shfl(ssum, h0 << 4), s1 = __shfl(ssum, h1 << 4);
    int c0 = lane, c1 = lane + 64;
    float acc0 = 0.f, acc1 = 0.f;
    for (int li = 0; li < deg; li++) {
        int s; float w0, w1;
        if (li < CW) {
            s = ssrc[wv][li];
            w0 = sexp[wv][li][h0]; w1 = sexp[wv][li][h1];
        } else {
            s = csrs[b + li];
            w0 = expf(lrelu(el[(size_t)s * 4 + h0] + ((const float*)&er4)[h0]) - m0);
            w1 = expf(lrelu(el[(size_t)s * 4 + h1] + ((const float*)&er4)[h1]) - m1);
        }
        int su = __builtin_amdgcn_readfirstlane(s);
        const float* zr = z + (size_t)su * HD;
        acc0 = fmaf(w0, zr[c0], acc0);
        acc1 = fmaf(w1, zr[c1], acc1);
    }
    float xc0 = acc0 / fmaxf(s0, 1e-16f) + bias[c0];
    float xc1 = acc1 / fmaxf(s1, 1e-16f) + bias[c1];
    float t = xc0 + xc1;              // x[c]+x[c+64]
    t += __shfl_xor(t, 32);           // + x[c+32]+x[c+96]
    float pg = 0.f;
    if (lane < 32) {
        float r = 0.25f * t;
        res[(size_t)v * 32 + lane] = r;
        pg = r * gW[lane];
    }
#pragma unroll
    for (int o = 1; o < 32; o <<= 1) pg += __shfl_xor(pg, o);
    if (lane == 0) g[v] = pg + gb[0];
}

// per-edge alpha outputs: pure reads, writes atten+strength for ALL edges
__global__ void k_ealpha1(P p) {
    int e = blockIdx.x * blockDim.x + threadIdx.x;
    if (e >= EE) return;
    int ds = p.slot[p.src[e]], dd = p.slot[p.dst[e]];
    float a[4] = {0.f, 0.f, 0.f, 0.f};
    float st = 0.f;
    if (ds >= 0 && dd >= 0) {
        float4 es = *(const float4*)(p.el1 + ds * 4);
        float4 ed = *(const float4*)(p.er1 + dd * 4);
        float l[4] = {lrelu(es.x + ed.x), lrelu(es.y + ed.y), lrelu(es.z + ed.z), lrelu(es.w + ed.w)};
#pragma unroll
        for (int h = 0; h < 4; h++) {
            float m = p.m1f[dd * 4 + h];
            float ex = expf(l[h] - m);
            a[h] = ex / fmaxf(p.s1f[dd * 4 + h], 1e-16f);
        }
        st = p.strength[e];
    }
    float* o = p.out + ATT_OFF + (size_t)e * 4;
    *(float2*)(o) = make_float2(a[0], a[1]);
    *(float2*)(o + 2) = make_float2(a[2], a[3]);
    p.out[STR_OFF + e] = st;
}

// ---------- readout ----------
__global__ void k_gmax(P p) {
    __shared__ float red[256];
    int t = threadIdx.x;
    float m = -3.4e38f;
    for (int i = blockIdx.x * 256 + t; i < KK; i += gridDim.x * 256) m = fmaxf(m, p.g[i]);
    red[t] = m;
    __syncthreads();
    for (int o = 128; o > 0; o >>= 1) { if (t < o) red[t] = fmaxf(red[t], red[t + o]); __syncthreads(); }
    if (t == 0) atomicMax(p.gmaxk, fkey(red[0]));   // memset-0 identity ok
}
#define WSUM_BLOCKS 104
__global__ __launch_bounds__(256) void k_wsum(P p) {
    __shared__ double vred[256];
    __shared__ double zred[8];
    int t = threadIdx.x, il = t >> 5, d = t & 31;
    float gm = unfkey(*p.gmaxk);
    double accv = 0.0, accw = 0.0;
    for (int i = blockIdx.x * 8 + il; i < KK; i += WSUM_BLOCKS * 8) {
        float w = expf(p.g[i] - gm);
        accv += (double)(w * p.res[(size_t)i * 32 + d]);
        if (d == 0) accw += (double)w;
    }
    vred[t] = accv;
    if (d == 0) zred[il] = accw;
    __syncthreads();
    if (il == 0) {
        double s = 0;
#pragma unroll
        for (int k2 = 0; k2 < 8; k2++) s += vred[k2 * 32 + d];
        atomicAdd(&p.racc[d], s);
    }
    if (t == 32) {
        double z2 = 0;
#pragma unroll
        for (int k2 = 0; k2 < 8; k2++) z2 += zred[k2];
        atomicAdd(p.Zacc, z2);
    }
}
__global__ void k_final(P p) {
    __shared__ float rb[32];
    int t = threadIdx.x;
    double Z = *p.Zacc;
    if (t < 32) {
        float r = (float)(p.racc[t] / Z);
        p.out[t] = r;
        rb[t] = r;
    }
    __syncthreads();
    if (t < 2) {
        float s = 0.f;
        for (int d = 0; d < 32; d++) s += rb[d] * p.cW[d * 2 + t];
        p.out[32 + t] = s + p.cb[t];
    }
}

// ---------- host ----------
extern "C" void kernel_launch(void* const* d_in, const int* in_sizes, int n_in,
                              void* d_out, int out_size, void* d_ws, size_t ws_size,
                              hipStream_t stream) {
    (void)in_sizes; (void)n_in; (void)out_size; (void)ws_size;
    P p;
    p.feature  = (const float*)d_in[0];
    p.strength = (const float*)d_in[1];
    p.W0  = (const float*)d_in[2];  p.b0  = (const float*)d_in[3];
    p.al0 = (const float*)d_in[4];  p.ar0 = (const float*)d_in[5];
    p.Wc0 = (const float*)d_in[6];  p.bc0 = (const float*)d_in[7];
    p.W1  = (const float*)d_in[8];  p.b1  = (const float*)d_in[9];
    p.al1 = (const float*)d_in[10]; p.ar1 = (const float*)d_in[11];
    p.gW  = (const float*)d_in[12]; p.gb  = (const float*)d_in[13];
    p.cW  = (const float*)d_in[14]; p.cb  = (const float*)d_in[15];
    p.src = (const int*)d_in[16];   p.dst = (const int*)d_in[17];
    p.out = (float*)d_out;

    char* ws = (char*)d_ws;
    size_t off = 0;
    auto alloc = [&](size_t bytes) -> void* {
        void* r = ws + off;
        off = (off + bytes + 255) & ~(size_t)255;
        return r;
    };
    // ---- zeroed region (must stay first/contiguous) ----
    p.Zacc  = (double*)alloc(8);
    p.racc  = (double*)alloc(32 * 8);
    p.deg_i = (int*)alloc((size_t)NN * 4);
    p.deg_o = (int*)alloc((size_t)NN * 4);
    p.cur0  = (int*)alloc((size_t)NN * 4);
    p.deg1  = (int*)alloc((size_t)KK * 4);
    p.cur1  = (int*)alloc((size_t)KK * 4);
    p.cnt   = (int*)alloc(4);
    p.gmaxk = (unsigned*)alloc(4);
    p.rs    = (unsigned*)alloc(16);
    p.binsHi = (unsigned*)alloc(65536 * 4);
    p.binsLo = (unsigned*)alloc(65536 * 4);
    size_t zbytes = off;
    // ---- big buffers ----
    p.z0 = (float*)alloc((size_t)NN * HD * 4);
    p.xk = (float*)alloc((size_t)KK * HD * 4);
    p.z1 = (float*)alloc((size_t)KK * HD * 4);
    p.csr_src = (int*)alloc((size_t)EE * 4);
    p.el0 = (float*)alloc((size_t)NN * 4 * 4);
    p.er0 = (float*)alloc((size_t)NN * 4 * 4);
    p.q4  = (float*)alloc((size_t)NN * 4 * 4);
    p.m0f = (float*)alloc((size_t)NN * 4 * 4);
    p.s0f = (float*)alloc((size_t)NN * 4 * 4);
    p.b0wc = (float*)alloc(4);
    p.off0 = (int*)alloc((size_t)(NN + 1) * 4);
    p.off1 = (int*)alloc((size_t)(KK + 1) * 4);
    p.hc    = (float*)alloc((size_t)NN * 4);
    p.score = (float*)alloc((size_t)NN * 4);
    p.keys  = (unsigned*)alloc((size_t)NN * 4);
    p.sel   = (int*)alloc((size_t)NN * 4);
    p.slot  = (int*)alloc((size_t)NN * 4);
    p.list  = (int*)alloc((size_t)KK * 4);
    p.tscale = (float*)alloc((size_t)KK * 4);
    p.el1 = (float*)alloc((size_t)KK * 4 * 4);
    p.er1 = (float*)alloc((size_t)KK * 4 * 4);
    p.m1f = (float*)alloc((size_t)KK * 4 * 4);
    p.s1f = (float*)alloc((size_t)KK * 4 * 4);
    p.res = (float*)alloc((size_t)KK * DD * 4);
    p.g   = (float*)alloc((size_t)KK * 4);

    const int GB_E = (EE + 255) / 256;        // 3125
    const int GB_N = (NN + 255) / 256;        // 196

    hipMemsetAsync(d_ws, 0, zbytes, stream);

    // ---- GAT layer 0 ----
    k_gemm<<<dim3(2, (NN + BM - 1) / BM), 256, 0, stream>>>(
        p.feature, p.W0, p.z0, NN, FIN, p.al0, p.ar0, p.el0, p.er0, p.Wc0, p.q4);
    k_prep<<<1, 64, 0, stream>>>(p.b0, p.Wc0, p.b0wc);
    k_deg<<<GB_E, 256, 0, stream>>>(p);
    k_scan<<<1, 1024, 0, stream>>>(p.deg_i, p.off0, NN);
    k_scatter0<<<GB_E, 256, 0, stream>>>(p);
    k_fgatlite<<<NN / 4, 256, 0, stream>>>(p.off0, p.csr_src, p.el0, p.er0, p.q4,
                                           p.deg_o, p.b0wc, p.hc, p.m0f, p.s0f);

    // ---- SAGPool ----
    k_score<<<GB_N, 256, 0, stream>>>(p);
    k_hist2<<<GB_N, 256, 0, stream>>>(p, 0);
    k_rsel2<<<1, 1024, 0, stream>>>(p, 0);
    k_hist2<<<GB_N, 256, 0, stream>>>(p, 1);
    k_rsel2<<<1, 1024, 0, stream>>>(p, 1);
    k_sel<<<GB_N, 256, 0, stream>>>(p);
    k_ties<<<1, 1024, 0, stream>>>(p);
    k_list<<<GB_N, 256, 0, stream>>>(p);
    k_fgatx<<<KK / 4, 256, 0, stream>>>(p.list, p.tscale, p.off0, p.csr_src,
                                        p.el0, p.er0, p.m0f, p.s0f, p.z0, p.b0, p.xk);

    // ---- GAT layer 1 ----
    k_gemm<<<dim3(2, (KK + BM - 1) / BM), 256, 0, stream>>>(
        p.xk, p.W1, p.z1, KK, HD, p.al1, p.ar1, p.el1, p.er1, nullptr, nullptr);
    k_deg1<<<GB_E, 256, 0, stream>>>(p);
    k_scan<<<1, 1024, 0, stream>>>(p.deg1, p.off1, KK);
    k_scatter1<<<GB_E, 256, 0, stream>>>(p);
    k_fgat2<<<KK / 4, 256, 0, stream>>>(p.off1, p.csr_src, p.el1, p.er1, p.z1, p.b1,
                                        p.m1f, p.s1f, p.gW, p.gb, p.res, p.g);
    k_ealpha1<<<GB_E, 256, 0, stream>>>(p);

    // ---- readout ----
    k_gmax<<<98, 256, 0, stream>>>(p);
    k_wsum<<<WSUM_BLOCKS, 256, 0, stream>>>(p);
    k_final<<<1, 64, 0, stream>>>(p);
}

// Round 8
// 651.749 us; speedup vs baseline: 1.2189x; 1.1468x over previous
//
#include <hip/hip_runtime.h>
#include <stdint.h>

#define NN 50000
#define EE 800000
#define FIN 256
#define HD 128
#define DD 32
#define KK 25000
#define SLOPEF 0.4f
#define NEGF (-1e9f)
#define ATT_OFF 34
#define STR_OFF (34 + EE * 4)
#define CW 128             // LDS-cached edges per node (deg ~Poisson(16); recompute fallback)

// ---------- helpers ----------
__device__ __forceinline__ unsigned fkey(float x) {
    unsigned u = __float_as_uint(x);
    return (u & 0x80000000u) ? ~u : (u | 0x80000000u);   // monotone float->uint
}
__device__ __forceinline__ float unfkey(unsigned k) {
    unsigned u = (k & 0x80000000u) ? (k ^ 0x80000000u) : ~k;
    return __uint_as_float(u);
}
__device__ __forceinline__ float lrelu(float v) { return v > 0.f ? v : SLOPEF * v; }

// ---------- pointer bundle ----------
struct P {
    // inputs
    const float *feature, *strength, *W0, *b0, *al0, *ar0, *Wc0, *bc0;
    const float *W1, *b1, *al1, *ar1, *gW, *gb, *cW, *cb;
    const int *src, *dst;
    // zeroed scratch
    double *Zacc, *racc;
    int *deg_i, *deg_o, *cur0, *deg1, *cur1, *cnt;
    unsigned *gmaxk, *rs;         // rs[0]=pivot key, rs[1]=ties needed, rs[2]=hi bin, rs[3]=hi remaining
    unsigned *binsHi, *binsLo;
    // other scratch
    unsigned *keys;
    int *csr_src, *off0, *off1, *sel, *slot, *list, *bsum, *boff;
    float *z0, *el0, *er0, *q4, *m0f, *s0f, *b0wc, *hc, *score, *xk, *z1;
    float *el1, *er1, *m1f, *s1f, *res, *g, *tscale;
    float *out;                    // d_out (float32)
};

// ---------- fp32 tiled GEMM: C[M,128] = A[M,Kd] @ B[Kd,128] ----------
// ELR epilogue: el/er for this block's 2 heads from acc regs; optional q4
// (per-head z.Wc chunks) for the SAGPool scalar-score path.
#define BM 128
#define BN 64
#define BK 16
__global__ __launch_bounds__(256) void k_gemm(
    const float* __restrict__ A, const float* __restrict__ B, float* __restrict__ C,
    int M, int Kd,
    const float* __restrict__ al, const float* __restrict__ ar,
    float* __restrict__ el, float* __restrict__ er,
    const float* __restrict__ Wc, float* __restrict__ q4) {
    __shared__ float As[BK][BM + 4];
    __shared__ float Bs[BK][BN];
    int bm = blockIdx.y * BM, bn = blockIdx.x * BN;
    int tid = threadIdx.x;
    int tr = tid >> 4, tc = tid & 15;
    int lrow = tid >> 1;
    int arow = (bm + lrow < M) ? (bm + lrow) : -1;
    float acc[8][4] = {};
    for (int k0 = 0; k0 < Kd; k0 += BK) {
        {
            int col = (tid & 1) << 3;
            float4 v0 = {0.f,0.f,0.f,0.f}, v1 = {0.f,0.f,0.f,0.f};
            if (arow >= 0) {
                const float* ap = A + (size_t)arow * Kd + k0 + col;
                v0 = *(const float4*)ap; v1 = *(const float4*)(ap + 4);
            }
            As[col + 0][lrow] = v0.x; As[col + 1][lrow] = v0.y;
            As[col + 2][lrow] = v0.z; As[col + 3][lrow] = v0.w;
            As[col + 4][lrow] = v1.x; As[col + 5][lrow] = v1.y;
            As[col + 6][lrow] = v1.z; As[col + 7][lrow] = v1.w;
        }
        {
            int kr = tid >> 4, col = (tid & 15) << 2;
            float4 v = *(const float4*)(B + (size_t)(k0 + kr) * HD + bn + col);
            *(float4*)&Bs[kr][col] = v;
        }
        __syncthreads();
#pragma unroll
        for (int kk = 0; kk < BK; kk++) {
            float a[8], b[4];
#pragma unroll
            for (int i = 0; i < 8; i++) a[i] = As[kk][tr * 8 + i];
#pragma unroll
            for (int j = 0; j < 4; j++) b[j] = Bs[kk][tc * 4 + j];
#pragma unroll
            for (int i = 0; i < 8; i++)
#pragma unroll
                for (int j = 0; j < 4; j++) acc[i][j] = fmaf(a[i], b[j], acc[i][j]);
        }
        __syncthreads();
    }
#pragma unroll
    for (int i = 0; i < 8; i++) {
        int gr = bm + tr * 8 + i;
        if (gr < M) {
            float4 v = {acc[i][0], acc[i][1], acc[i][2], acc[i][3]};
            *(float4*)(C + (size_t)gr * HD + bn + tc * 4) = v;
        }
    }
    // epilogue: heads 2*bx, 2*bx+1; 8-lane tree reduce per (row, head)
    int head = blockIdx.x * 2 + (tc >> 3);
    int dbase = (tc & 7) * 4;
    const float* alh = al + head * 32 + dbase;
    const float* arh = ar + head * 32 + dbase;
    float a0 = alh[0], a1 = alh[1], a2 = alh[2], a3 = alh[3];
    float r0 = arh[0], r1 = arh[1], r2 = arh[2], r3 = arh[3];
    float w0 = 0.f, w1 = 0.f, w2 = 0.f, w3 = 0.f;
    if (Wc) {
        const float* wch = Wc + head * 32 + dbase;
        w0 = wch[0]; w1 = wch[1]; w2 = wch[2]; w3 = wch[3];
    }
#pragma unroll
    for (int i = 0; i < 8; i++) {
        int gr = bm + tr * 8 + i;
        float pe = acc[i][0]*a0 + acc[i][1]*a1 + acc[i][2]*a2 + acc[i][3]*a3;
        float pr = acc[i][0]*r0 + acc[i][1]*r1 + acc[i][2]*r2 + acc[i][3]*r3;
        float pq = acc[i][0]*w0 + acc[i][1]*w1 + acc[i][2]*w2 + acc[i][3]*w3;
#pragma unroll
        for (int o = 1; o < 8; o <<= 1) {
            pe += __shfl_xor(pe, o); pr += __shfl_xor(pr, o); pq += __shfl_xor(pq, o);
        }
        if ((tc & 7) == 0 && gr < M) {
            el[gr * 4 + head] = pe; er[gr * 4 + head] = pr;
            if (Wc) q4[gr * 4 + head] = pq;
        }
    }
}

// ---------- b0.Wc0 scalar ----------
__global__ void k_prep(const float* __restrict__ b0, const float* __restrict__ Wc,
                       float* __restrict__ b0wc) {
    int l = threadIdx.x;
    float t = b0[l] * Wc[l] + b0[l + 64] * Wc[l + 64];
#pragma unroll
    for (int o = 1; o < 64; o <<= 1) t += __shfl_xor(t, o);
    if (l == 0) b0wc[0] = t;
}

// ---------- degrees ----------
__global__ void k_deg(P p) {
    int e = blockIdx.x * blockDim.x + threadIdx.x;
    if (e >= EE) return;
    atomicAdd(&p.deg_i[p.dst[e]], 1);
    atomicAdd(&p.deg_o[p.src[e]], 1);
}

// ---------- two-level exclusive scan (replaces 76us single-block k_scan) ----------
// R7 lesson: 1-block scan = 0.15% occupancy, stride-49 uncoalesced, serial
// dep chain on non-local-L2 data -> 76us. Coalesced 3-kernel scan ~10us.
__global__ __launch_bounds__(256) void k_bsum(const int* __restrict__ deg,
                                              int* __restrict__ bsum, int n) {
    int i = blockIdx.x * 256 + threadIdx.x;
    int v = (i < n) ? deg[i] : 0;
    int lane = threadIdx.x & 63, w = threadIdx.x >> 6;
    __shared__ int ws[4];
#pragma unroll
    for (int o = 1; o < 64; o <<= 1) v += __shfl_xor(v, o);
    if (lane == 0) ws[w] = v;
    __syncthreads();
    if (threadIdx.x == 0) bsum[blockIdx.x] = ws[0] + ws[1] + ws[2] + ws[3];
}
__global__ __launch_bounds__(256) void k_bscan(const int* __restrict__ bsum, int nb,
                                               int* __restrict__ boff,
                                               int* __restrict__ off, int n) {
    __shared__ int ws[4];
    __shared__ int wo[5];
    int t = threadIdx.x;
    int v = (t < nb) ? bsum[t] : 0;
    int lane = t & 63, w = t >> 6;
    int incl = v;
    for (int o = 1; o < 64; o <<= 1) { int u = __shfl_up(incl, o); if (lane >= o) incl += u; }
    if (lane == 63) ws[w] = incl;
    __syncthreads();
    if (t == 0) { int a = 0; for (int i = 0; i < 4; i++) { wo[i] = a; a += ws[i]; } wo[4] = a; }
    __syncthreads();
    if (t < nb) boff[t] = wo[w] + incl - v;
    if (t == 0) off[n] = wo[4];
}
__global__ __launch_bounds__(256) void k_fscan(const int* __restrict__ deg,
                                               const int* __restrict__ boff,
                                               int* __restrict__ off, int n) {
    __shared__ int ws[4];
    __shared__ int wo[4];
    int i = blockIdx.x * 256 + threadIdx.x;
    int v = (i < n) ? deg[i] : 0;
    int lane = threadIdx.x & 63, w = threadIdx.x >> 6;
    int incl = v;
    for (int o = 1; o < 64; o <<= 1) { int u = __shfl_up(incl, o); if (lane >= o) incl += u; }
    if (lane == 63) ws[w] = incl;
    __syncthreads();
    if (threadIdx.x == 0) { int a = 0; for (int k = 0; k < 4; k++) { wo[k] = a; a += ws[k]; } }
    __syncthreads();
    if (i < n) off[i] = boff[blockIdx.x] + wo[w] + incl - v;
}

// ---------- CSR scatter (src-ids only) ----------
__global__ void k_scatter0(P p) {
    int e = blockIdx.x * blockDim.x + threadIdx.x;
    if (e >= EE) return;
    int d = p.dst[e];
    int pos = p.off0[d] + atomicAdd(&p.cur0[d], 1);
    p.csr_src[pos] = p.src[e];
}

// ---------- layer-0 softmax + SCALAR q-gather (all nodes) ----------
__global__ __launch_bounds__(256) void k_fgatlite(
    const int* __restrict__ off, const int* __restrict__ csrs,
    const float* __restrict__ el, const float* __restrict__ er,
    const float* __restrict__ q4, const int* __restrict__ dego,
    const float* __restrict__ b0wc,
    float* __restrict__ hc, float* __restrict__ m0f, float* __restrict__ s0f) {
    int wv = threadIdx.x >> 6, lane = threadIdx.x & 63;
    int v = blockIdx.x * 4 + wv;
    int b = off[v], e = off[v + 1], deg = e - b;
    int h = lane >> 4, sub = lane & 15;
    float erh = er[(size_t)v * 4 + h];
    float m = NEGF;
    for (int li = sub; li < deg; li += 16) {
        int s = csrs[b + li];
        m = fmaxf(m, lrelu(el[(size_t)s * 4 + h] + erh));
    }
#pragma unroll
    for (int o = 1; o < 16; o <<= 1) m = fmaxf(m, __shfl_xor(m, o));
    float ssum = 0.f, hq = 0.f;
    for (int li = sub; li < deg; li += 16) {
        int s = csrs[b + li];
        float ex = expf(lrelu(el[(size_t)s * 4 + h] + erh) - m);
        ssum += ex;
        hq = fmaf(ex, q4[(size_t)s * 4 + h], hq);
    }
#pragma unroll
    for (int o = 1; o < 16; o <<= 1) { ssum += __shfl_xor(ssum, o); hq += __shfl_xor(hq, o); }
    if (sub == 0) { m0f[v * 4 + h] = m; s0f[v * 4 + h] = ssum; }
    float t = hq / fmaxf(ssum, 1e-16f);     // uniform within head group
    t += __shfl_xor(t, 16);
    t += __shfl_xor(t, 32);                 // sum over 4 heads
    if (lane == 0)
        hc[v] = (t + b0wc[0]) / sqrtf(fmaxf((float)dego[v], 1.f));
}

// ---------- full x for SELECTED nodes only ----------
__global__ __launch_bounds__(256) void k_fgatx(
    const int* __restrict__ list, const float* __restrict__ tscale,
    const int* __restrict__ off, const int* __restrict__ csrs,
    const float* __restrict__ el, const float* __restrict__ er,
    const float* __restrict__ m0f, const float* __restrict__ s0f,
    const float* __restrict__ z, const float* __restrict__ b0,
    float* __restrict__ xk) {
    __shared__ int ssrc[4][CW];
    __shared__ float sexp[4][CW][4];
    int wv = threadIdx.x >> 6, lane = threadIdx.x & 63;
    int i = blockIdx.x * 4 + wv;
    int v = list[i];
    int b = off[v], e = off[v + 1], deg = e - b;
    int h = lane >> 4, sub = lane & 15;
    float erh = er[(size_t)v * 4 + h];
    float mh = m0f[v * 4 + h];
    for (int li = sub; li < deg; li += 16) {
        int s = csrs[b + li];
        if (h == 0 && li < CW) ssrc[wv][li] = s;
        if (li < CW) sexp[wv][li][h] = expf(lrelu(el[(size_t)s * 4 + h] + erh) - mh);
    }
    __syncthreads();
    int h0 = lane >> 5, h1 = h0 + 2;
    float s0 = s0f[v * 4 + h0], s1 = s0f[v * 4 + h1];
    float m0 = m0f[v * 4 + h0], m1 = m0f[v * 4 + h1];
    float er0v = er[(size_t)v * 4 + h0], er1v = er[(size_t)v * 4 + h1];
    int c0 = lane, c1 = lane + 64;
    float acc0 = 0.f, acc1 = 0.f;
    for (int li = 0; li < deg; li++) {
        int s; float w0, w1;
        if (li < CW) {
            s = ssrc[wv][li];
            w0 = sexp[wv][li][h0]; w1 = sexp[wv][li][h1];
        } else {
            s = csrs[b + li];
            w0 = expf(lrelu(el[(size_t)s * 4 + h0] + er0v) - m0);
            w1 = expf(lrelu(el[(size_t)s * 4 + h1] + er1v) - m1);
        }
        int su = __builtin_amdgcn_readfirstlane(s);
        const float* zr = z + (size_t)su * HD;
        acc0 = fmaf(w0, zr[c0], acc0);
        acc1 = fmaf(w1, zr[c1], acc1);
    }
    float ts = tscale[i];
    float* xr = xk + (size_t)i * HD;
    xr[c0] = (acc0 / fmaxf(s0, 1e-16f) + b0[c0]) * ts;
    xr[c1] = (acc1 / fmaxf(s1, 1e-16f) + b0[c1]) * ts;
}

// ---------- SAGPool score ----------
__global__ void k_score(P p) {
    int v = blockIdx.x * blockDim.x + threadIdx.x;
    if (v >= NN) return;
    int b = p.off0[v], en = p.off0[v + 1];
    float acc = 0.f;
    for (int i = b; i < en; i++) acc += p.hc[p.csr_src[i]];
    float dg = fmaxf((float)(en - b), 1.f);
    float sc = acc / sqrtf(dg) + p.bc0[0];
    p.score[v] = sc;
    p.keys[v] = fkey(sc);
}

// ---------- radix select: 2 x 16-bit passes ----------
__global__ void k_hist2(P p, int level) {
    int v = blockIdx.x * blockDim.x + threadIdx.x;
    if (v >= NN) return;
    unsigned key = p.keys[v];
    if (level == 0) atomicAdd(&p.binsHi[key >> 16], 1u);
    else if ((key >> 16) == p.rs[2]) atomicAdd(&p.binsLo[key & 0xFFFFu], 1u);
}
__global__ __launch_bounds__(1024) void k_rsel2(P p, int level) {
    const unsigned* bins = level ? p.binsLo : p.binsHi;
    int K = level ? (int)p.rs[3] : KK;
    __shared__ unsigned wsm[16];
    __shared__ unsigned wpre[17];
    int t = threadIdx.x;
    unsigned base = (unsigned)t * 64;
    const uint4* b4 = (const uint4*)(bins + base);
    unsigned S = 0;
#pragma unroll
    for (int i = 0; i < 16; i++) {
        uint4 u = b4[i];
        S += u.x + u.y + u.z + u.w;
    }
    int lane = t & 63, w = t >> 6;
    unsigned val = S;
    for (int o = 1; o < 64; o <<= 1) { unsigned u = __shfl_up(val, o); if (lane >= o) val += u; }
    if (lane == 63) wsm[w] = val;
    __syncthreads();
    if (t == 0) { unsigned a = 0; for (int i = 0; i < 16; i++) { wpre[i] = a; a += wsm[i]; } wpre[16] = a; }
    __syncthreads();
    unsigned incl = wpre[w] + val;
    unsigned running = wpre[16] - incl;    // keys in strictly higher bins
    for (int i = 63; i >= 0; i--) {
        unsigned c = bins[base + i];
        unsigned above = running;
        running += c;
        if ((int)above < K && (int)running >= K) {
            if (level == 0) { p.rs[2] = base + (unsigned)i; p.rs[3] = (unsigned)(K - (int)above); }
            else { p.rs[0] = (p.rs[2] << 16) | (base + (unsigned)i); p.rs[1] = (unsigned)(K - (int)above); }
        }
    }
}
__global__ void k_sel(P p) {
    int v = blockIdx.x * blockDim.x + threadIdx.x;
    if (v >= NN) return;
    p.sel[v] = (p.keys[v] > p.rs[0]) ? 1 : 0;
}
__global__ __launch_bounds__(1024) void k_ties(P p) {   // lowest-index ties (matches top_k)
    __shared__ int base;
    __shared__ int wsums[16];
    unsigned pivot = p.rs[0];
    int need = (int)p.rs[1];
    if (threadIdx.x == 0) base = 0;
    __syncthreads();
    for (int st = 0; st < NN; st += 1024) {
        int v = st + (int)threadIdx.x;
        int flag = (v < NN && p.keys[v] == pivot) ? 1 : 0;
        unsigned long long m = __ballot(flag);
        int lane = threadIdx.x & 63, w = threadIdx.x >> 6;
        int pre = __popcll(m & ((1ull << lane) - 1ull));
        if (lane == 0) wsums[w] = __popcll(m);
        __syncthreads();
        int woff = 0;
        for (int i = 0; i < w; i++) woff += wsums[i];
        int rank = base + woff + pre;
        if (flag && rank < need) p.sel[v] = 1;
        __syncthreads();
        if (threadIdx.x == 0) {
            int s = 0;
            for (int i = 0; i < 16; i++) s += wsums[i];
            base += s;
        }
        __syncthreads();
    }
}
__global__ void k_list(P p) {
    int v = blockIdx.x * blockDim.x + threadIdx.x;
    if (v >= NN) return;
    if (p.sel[v]) {
        int i = atomicAdd(p.cnt, 1);
        p.list[i] = v;
        p.slot[v] = i;
        p.tscale[i] = tanhf(p.score[v]);
    } else {
        p.slot[v] = -1;
    }
}

// ---------- layer-1 graph (valid edges only, slot-indexed) ----------
__global__ void k_deg1(P p) {
    int e = blockIdx.x * blockDim.x + threadIdx.x;
    if (e >= EE) return;
    int ds = p.slot[p.src[e]], dd = p.slot[p.dst[e]];
    if (ds >= 0 && dd >= 0) atomicAdd(&p.deg1[dd], 1);
}
__global__ void k_scatter1(P p) {
    int e = blockIdx.x * blockDim.x + threadIdx.x;
    if (e >= EE) return;
    int ds = p.slot[p.src[e]], dd = p.slot[p.dst[e]];
    if (ds >= 0 && dd >= 0) {
        int pos = p.off1[dd] + atomicAdd(&p.cur1[dd], 1);
        p.csr_src[pos] = ds;
    }
}

// ---------- layer-1 fused GAT (wave-per-node) + res/g epilogue ----------
__global__ __launch_bounds__(256) void k_fgat2(
    const int* __restrict__ off, const int* __restrict__ csrs,
    const float* __restrict__ el, const float* __restrict__ er,
    const float* __restrict__ z, const float* __restrict__ bias,
    float* __restrict__ mf, float* __restrict__ sf,
    const float* __restrict__ gW, const float* __restrict__ gb,
    float* __restrict__ res, float* __restrict__ g) {
    __shared__ int ssrc[4][CW];
    __shared__ float sexp[4][CW][4];
    int wv = threadIdx.x >> 6, lane = threadIdx.x & 63;
    int v = blockIdx.x * 4 + wv;
    int b = off[v], e = off[v + 1], deg = e - b;
    int h = lane >> 4, sub = lane & 15;
    float4 er4 = *(const float4*)(er + (size_t)v * 4);
    float erh = ((const float*)&er4)[h];
    float m = NEGF;
    for (int li = sub; li < deg; li += 16) {
        int s = csrs[b + li];
        if (h == 0 && li < CW) ssrc[wv][li] = s;
        m = fmaxf(m, lrelu(el[(size_t)s * 4 + h] + erh));
    }
#pragma unroll
    for (int o = 1; o < 16; o <<= 1) m = fmaxf(m, __shfl_xor(m, o));
    float ssum = 0.f;
    for (int li = sub; li < deg; li += 16) {
        int s = csrs[b + li];
        float x = expf(lrelu(el[(size_t)s * 4 + h] + erh) - m);
        if (li < CW) sexp[wv][li][h] = x;
        ssum += x;
    }
#pragma unroll
    for (int o = 1; o < 16; o <<= 1) ssum += __shfl_xor(ssum, o);
    if (sub == 0) { mf[v * 4 + h] = m; sf[v * 4 + h] = ssum; }
    __syncthreads();
    int h0 = lane >> 5, h1 = h0 + 2;
    float m0 = __shfl(m, h0 << 4), m1 = __shfl(m, h1 << 4);
    float s0 = __shfl(ssum, h0 << 4), s1 = __shfl(ssum, h1 << 4);
    int c0 = lane, c1 = lane + 64;
    float acc0 = 0.f, acc1 = 0.f;
    for (int li = 0; li < deg; li++) {
        int s; float w0, w1;
        if (li < CW) {
            s = ssrc[wv][li];
            w0 = sexp[wv][li][h0]; w1 = sexp[wv][li][h1];
        } else {
            s = csrs[b + li];
            w0 = expf(lrelu(el[(size_t)s * 4 + h0] + ((const float*)&er4)[h0]) - m0);
            w1 = expf(lrelu(el[(size_t)s * 4 + h1] + ((const float*)&er4)[h1]) - m1);
        }
        int su = __builtin_amdgcn_readfirstlane(s);
        const float* zr = z + (size_t)su * HD;
        acc0 = fmaf(w0, zr[c0], acc0);
        acc1 = fmaf(w1, zr[c1], acc1);
    }
    float xc0 = acc0 / fmaxf(s0, 1e-16f) + bias[c0];
    float xc1 = acc1 / fmaxf(s1, 1e-16f) + bias[c1];
    float t = xc0 + xc1;              // x[c]+x[c+64]
    t += __shfl_xor(t, 32);           // + x[c+32]+x[c+96]
    float pg = 0.f;
    if (lane < 32) {
        float r = 0.25f * t;
        res[(size_t)v * 32 + lane] = r;
        pg = r * gW[lane];
    }
#pragma unroll
    for (int o = 1; o < 32; o <<= 1) pg += __shfl_xor(pg, o);
    if (lane == 0) g[v] = pg + gb[0];
}

// per-edge alpha outputs: pure reads, writes atten+strength for ALL edges
__global__ void k_ealpha1(P p) {
    int e = blockIdx.x * blockDim.x + threadIdx.x;
    if (e >= EE) return;
    int ds = p.slot[p.src[e]], dd = p.slot[p.dst[e]];
    float a[4] = {0.f, 0.f, 0.f, 0.f};
    float st = 0.f;
    if (ds >= 0 && dd >= 0) {
        float4 es = *(const float4*)(p.el1 + ds * 4);
        float4 ed = *(const float4*)(p.er1 + dd * 4);
        float l[4] = {lrelu(es.x + ed.x), lrelu(es.y + ed.y), lrelu(es.z + ed.z), lrelu(es.w + ed.w)};
#pragma unroll
        for (int h = 0; h < 4; h++) {
            float m = p.m1f[dd * 4 + h];
            float ex = expf(l[h] - m);
            a[h] = ex / fmaxf(p.s1f[dd * 4 + h], 1e-16f);
        }
        st = p.strength[e];
    }
    float* o = p.out + ATT_OFF + (size_t)e * 4;
    *(float2*)(o) = make_float2(a[0], a[1]);
    *(float2*)(o + 2) = make_float2(a[2], a[3]);
    p.out[STR_OFF + e] = st;
}

// ---------- readout ----------
__global__ void k_gmax(P p) {
    __shared__ float red[256];
    int t = threadIdx.x;
    float m = -3.4e38f;
    for (int i = blockIdx.x * 256 + t; i < KK; i += gridDim.x * 256) m = fmaxf(m, p.g[i]);
    red[t] = m;
    __syncthreads();
    for (int o = 128; o > 0; o >>= 1) { if (t < o) red[t] = fmaxf(red[t], red[t + o]); __syncthreads(); }
    if (t == 0) atomicMax(p.gmaxk, fkey(red[0]));   // memset-0 identity ok
}
#define WSUM_BLOCKS 104
__global__ __launch_bounds__(256) void k_wsum(P p) {
    __shared__ double vred[256];
    __shared__ double zred[8];
    int t = threadIdx.x, il = t >> 5, d = t & 31;
    float gm = unfkey(*p.gmaxk);
    double accv = 0.0, accw = 0.0;
    for (int i = blockIdx.x * 8 + il; i < KK; i += WSUM_BLOCKS * 8) {
        float w = expf(p.g[i] - gm);
        accv += (double)(w * p.res[(size_t)i * 32 + d]);
        if (d == 0) accw += (double)w;
    }
    vred[t] = accv;
    if (d == 0) zred[il] = accw;
    __syncthreads();
    if (il == 0) {
        double s = 0;
#pragma unroll
        for (int k2 = 0; k2 < 8; k2++) s += vred[k2 * 32 + d];
        atomicAdd(&p.racc[d], s);
    }
    if (t == 32) {
        double z2 = 0;
#pragma unroll
        for (int k2 = 0; k2 < 8; k2++) z2 += zred[k2];
        atomicAdd(p.Zacc, z2);
    }
}
__global__ void k_final(P p) {
    __shared__ float rb[32];
    int t = threadIdx.x;
    double Z = *p.Zacc;
    if (t < 32) {
        float r = (float)(p.racc[t] / Z);
        p.out[t] = r;
        rb[t] = r;
    }
    __syncthreads();
    if (t < 2) {
        float s = 0.f;
        for (int d = 0; d < 32; d++) s += rb[d] * p.cW[d * 2 + t];
        p.out[32 + t] = s + p.cb[t];
    }
}

// ---------- host ----------
extern "C" void kernel_launch(void* const* d_in, const int* in_sizes, int n_in,
                              void* d_out, int out_size, void* d_ws, size_t ws_size,
                              hipStream_t stream) {
    (void)in_sizes; (void)n_in; (void)out_size; (void)ws_size;
    P p;
    p.feature  = (const float*)d_in[0];
    p.strength = (const float*)d_in[1];
    p.W0  = (const float*)d_in[2];  p.b0  = (const float*)d_in[3];
    p.al0 = (const float*)d_in[4];  p.ar0 = (const float*)d_in[5];
    p.Wc0 = (const float*)d_in[6];  p.bc0 = (const float*)d_in[7];
    p.W1  = (const float*)d_in[8];  p.b1  = (const float*)d_in[9];
    p.al1 = (const float*)d_in[10]; p.ar1 = (const float*)d_in[11];
    p.gW  = (const float*)d_in[12]; p.gb  = (const float*)d_in[13];
    p.cW  = (const float*)d_in[14]; p.cb  = (const float*)d_in[15];
    p.src = (const int*)d_in[16];   p.dst = (const int*)d_in[17];
    p.out = (float*)d_out;

    char* ws = (char*)d_ws;
    size_t off = 0;
    auto alloc = [&](size_t bytes) -> void* {
        void* r = ws + off;
        off = (off + bytes + 255) & ~(size_t)255;
        return r;
    };
    // ---- zeroed region (must stay first/contiguous) ----
    p.Zacc  = (double*)alloc(8);
    p.racc  = (double*)alloc(32 * 8);
    p.deg_i = (int*)alloc((size_t)NN * 4);
    p.deg_o = (int*)alloc((size_t)NN * 4);
    p.cur0  = (int*)alloc((size_t)NN * 4);
    p.deg1  = (int*)alloc((size_t)KK * 4);
    p.cur1  = (int*)alloc((size_t)KK * 4);
    p.cnt   = (int*)alloc(4);
    p.gmaxk = (unsigned*)alloc(4);
    p.rs    = (unsigned*)alloc(16);
    p.binsHi = (unsigned*)alloc(65536 * 4);
    p.binsLo = (unsigned*)alloc(65536 * 4);
    size_t zbytes = off;
    // ---- big buffers ----
    p.z0 = (float*)alloc((size_t)NN * HD * 4);
    p.xk = (float*)alloc((size_t)KK * HD * 4);
    p.z1 = (float*)alloc((size_t)KK * HD * 4);
    p.csr_src = (int*)alloc((size_t)EE * 4);
    p.el0 = (float*)alloc((size_t)NN * 4 * 4);
    p.er0 = (float*)alloc((size_t)NN * 4 * 4);
    p.q4  = (float*)alloc((size_t)NN * 4 * 4);
    p.m0f = (float*)alloc((size_t)NN * 4 * 4);
    p.s0f = (float*)alloc((size_t)NN * 4 * 4);
    p.b0wc = (float*)alloc(4);
    p.off0 = (int*)alloc((size_t)(NN + 1) * 4);
    p.off1 = (int*)alloc((size_t)(KK + 1) * 4);
    p.bsum = (int*)alloc(256 * 4);
    p.boff = (int*)alloc(256 * 4);
    p.hc    = (float*)alloc((size_t)NN * 4);
    p.score = (float*)alloc((size_t)NN * 4);
    p.keys  = (unsigned*)alloc((size_t)NN * 4);
    p.sel   = (int*)alloc((size_t)NN * 4);
    p.slot  = (int*)alloc((size_t)NN * 4);
    p.list  = (int*)alloc((size_t)KK * 4);
    p.tscale = (float*)alloc((size_t)KK * 4);
    p.el1 = (float*)alloc((size_t)KK * 4 * 4);
    p.er1 = (float*)alloc((size_t)KK * 4 * 4);
    p.m1f = (float*)alloc((size_t)KK * 4 * 4);
    p.s1f = (float*)alloc((size_t)KK * 4 * 4);
    p.res = (float*)alloc((size_t)KK * DD * 4);
    p.g   = (float*)alloc((size_t)KK * 4);

    const int GB_E = (EE + 255) / 256;        // 3125
    const int GB_N = (NN + 255) / 256;        // 196
    const int GB_K = (KK + 255) / 256;        // 98

    hipMemsetAsync(d_ws, 0, zbytes, stream);

    // ---- GAT layer 0 ----
    k_gemm<<<dim3(2, (NN + BM - 1) / BM), 256, 0, stream>>>(
        p.feature, p.W0, p.z0, NN, FIN, p.al0, p.ar0, p.el0, p.er0, p.Wc0, p.q4);
    k_prep<<<1, 64, 0, stream>>>(p.b0, p.Wc0, p.b0wc);
    k_deg<<<GB_E, 256, 0, stream>>>(p);
    k_bsum<<<GB_N, 256, 0, stream>>>(p.deg_i, p.bsum, NN);
    k_bscan<<<1, 256, 0, stream>>>(p.bsum, GB_N, p.boff, p.off0, NN);
    k_fscan<<<GB_N, 256, 0, stream>>>(p.deg_i, p.boff, p.off0, NN);
    k_scatter0<<<GB_E, 256, 0, stream>>>(p);
    k_fgatlite<<<NN / 4, 256, 0, stream>>>(p.off0, p.csr_src, p.el0, p.er0, p.q4,
                                           p.deg_o, p.b0wc, p.hc, p.m0f, p.s0f);

    // ---- SAGPool ----
    k_score<<<GB_N, 256, 0, stream>>>(p);
    k_hist2<<<GB_N, 256, 0, stream>>>(p, 0);
    k_rsel2<<<1, 1024, 0, stream>>>(p, 0);
    k_hist2<<<GB_N, 256, 0, stream>>>(p, 1);
    k_rsel2<<<1, 1024, 0, stream>>>(p, 1);
    k_sel<<<GB_N, 256, 0, stream>>>(p);
    k_ties<<<1, 1024, 0, stream>>>(p);
    k_list<<<GB_N, 256, 0, stream>>>(p);
    k_fgatx<<<KK / 4, 256, 0, stream>>>(p.list, p.tscale, p.off0, p.csr_src,
                                        p.el0, p.er0, p.m0f, p.s0f, p.z0, p.b0, p.xk);

    // ---- GAT layer 1 ----
    k_gemm<<<dim3(2, (KK + BM - 1) / BM), 256, 0, stream>>>(
        p.xk, p.W1, p.z1, KK, HD, p.al1, p.ar1, p.el1, p.er1, nullptr, nullptr);
    k_deg1<<<GB_E, 256, 0, stream>>>(p);
    k_bsum<<<GB_K, 256, 0, stream>>>(p.deg1, p.bsum, KK);
    k_bscan<<<1, 256, 0, stream>>>(p.bsum, GB_K, p.boff, p.off1, KK);
    k_fscan<<<GB_K, 256, 0, stream>>>(p.deg1, p.boff, p.off1, KK);
    k_scatter1<<<GB_E, 256, 0, stream>>>(p);
    k_fgat2<<<KK / 4, 256, 0, stream>>>(p.off1, p.csr_src, p.el1, p.er1, p.z1, p.b1,
                                        p.m1f, p.s1f, p.gW, p.gb, p.res, p.g);
    k_ealpha1<<<GB_E, 256, 0, stream>>>(p);

    // ---- readout ----
    k_gmax<<<98, 256, 0, stream>>>(p);
    k_wsum<<<WSUM_BLOCKS, 256, 0, stream>>>(p);
    k_final<<<1, 64, 0, stream>>>(p);
}

// Round 9
// 586.342 us; speedup vs baseline: 1.3548x; 1.1116x over previous
//
#include <hip/hip_runtime.h>
#include <stdint.h>

#define NN 50000
#define EE 800000
#define FIN 256
#define HD 128
#define DD 32
#define KK 25000
#define SLOPEF 0.4f
#define NEGF (-1e9f)
#define ATT_OFF 34
#define STR_OFF (34 + EE * 4)
#define CW 128             // LDS-cached edges per node (deg ~Poisson(16); recompute fallback)

// ---------- helpers ----------
__device__ __forceinline__ unsigned fkey(float x) {
    unsigned u = __float_as_uint(x);
    return (u & 0x80000000u) ? ~u : (u | 0x80000000u);   // monotone float->uint
}
__device__ __forceinline__ float unfkey(unsigned k) {
    unsigned u = (k & 0x80000000u) ? (k ^ 0x80000000u) : ~k;
    return __uint_as_float(u);
}
__device__ __forceinline__ float lrelu(float v) { return v > 0.f ? v : SLOPEF * v; }

// ---------- pointer bundle ----------
struct P {
    // inputs
    const float *feature, *strength, *W0, *b0, *al0, *ar0, *Wc0, *bc0;
    const float *W1, *b1, *al1, *ar1, *gW, *gb, *cW, *cb;
    const int *src, *dst;
    // zeroed scratch
    double *Zacc, *racc;
    int *deg_i, *deg_o, *deg1, *cnt;
    unsigned *gmaxk, *rs;         // rs[0]=pivot key, rs[1]=ties needed, rs[2]=hi bin, rs[3]=hi remaining
    unsigned *binsHi, *binsLo;
    // other scratch
    unsigned *keys;
    int *csr_src, *rank, *off0, *off1, *sel, *slot, *list, *bsum, *boff;
    float *z0, *el0, *er0, *q4, *m0f, *s0f, *b0wc, *hc, *score, *xk, *z1;
    float *el1, *er1, *m1f, *s1f, *res, *g, *tscale;
    float *out;                    // d_out (float32)
};

// ---------- fp32 tiled GEMM body: C[M,128] = A[M,Kd] @ B[Kd,128] ----------
// ELR epilogue: el/er for this block's 2 heads from acc regs; optional q4.
#define BM 128
#define BN 64
#define BK 16
__device__ void gemm_body(
    const float* __restrict__ A, const float* __restrict__ B, float* __restrict__ C,
    int M, int Kd,
    const float* __restrict__ al, const float* __restrict__ ar,
    float* __restrict__ el, float* __restrict__ er,
    const float* __restrict__ Wc, float* __restrict__ q4,
    int bx, int by) {
    __shared__ float As[BK][BM + 4];
    __shared__ float Bs[BK][BN];
    int bm = by * BM, bn = bx * BN;
    int tid = threadIdx.x;
    int tr = tid >> 4, tc = tid & 15;
    int lrow = tid >> 1;
    int arow = (bm + lrow < M) ? (bm + lrow) : -1;
    float acc[8][4] = {};
    for (int k0 = 0; k0 < Kd; k0 += BK) {
        {
            int col = (tid & 1) << 3;
            float4 v0 = {0.f,0.f,0.f,0.f}, v1 = {0.f,0.f,0.f,0.f};
            if (arow >= 0) {
                const float* ap = A + (size_t)arow * Kd + k0 + col;
                v0 = *(const float4*)ap; v1 = *(const float4*)(ap + 4);
            }
            As[col + 0][lrow] = v0.x; As[col + 1][lrow] = v0.y;
            As[col + 2][lrow] = v0.z; As[col + 3][lrow] = v0.w;
            As[col + 4][lrow] = v1.x; As[col + 5][lrow] = v1.y;
            As[col + 6][lrow] = v1.z; As[col + 7][lrow] = v1.w;
        }
        {
            int kr = tid >> 4, col = (tid & 15) << 2;
            float4 v = *(const float4*)(B + (size_t)(k0 + kr) * HD + bn + col);
            *(float4*)&Bs[kr][col] = v;
        }
        __syncthreads();
#pragma unroll
        for (int kk = 0; kk < BK; kk++) {
            float a[8], b[4];
#pragma unroll
            for (int i = 0; i < 8; i++) a[i] = As[kk][tr * 8 + i];
#pragma unroll
            for (int j = 0; j < 4; j++) b[j] = Bs[kk][tc * 4 + j];
#pragma unroll
            for (int i = 0; i < 8; i++)
#pragma unroll
                for (int j = 0; j < 4; j++) acc[i][j] = fmaf(a[i], b[j], acc[i][j]);
        }
        __syncthreads();
    }
#pragma unroll
    for (int i = 0; i < 8; i++) {
        int gr = bm + tr * 8 + i;
        if (gr < M) {
            float4 v = {acc[i][0], acc[i][1], acc[i][2], acc[i][3]};
            *(float4*)(C + (size_t)gr * HD + bn + tc * 4) = v;
        }
    }
    // epilogue: heads 2*bx, 2*bx+1; 8-lane tree reduce per (row, head)
    int head = bx * 2 + (tc >> 3);
    int dbase = (tc & 7) * 4;
    const float* alh = al + head * 32 + dbase;
    const float* arh = ar + head * 32 + dbase;
    float a0 = alh[0], a1 = alh[1], a2 = alh[2], a3 = alh[3];
    float r0 = arh[0], r1 = arh[1], r2 = arh[2], r3 = arh[3];
    float w0 = 0.f, w1 = 0.f, w2 = 0.f, w3 = 0.f;
    if (Wc) {
        const float* wch = Wc + head * 32 + dbase;
        w0 = wch[0]; w1 = wch[1]; w2 = wch[2]; w3 = wch[3];
    }
#pragma unroll
    for (int i = 0; i < 8; i++) {
        int gr = bm + tr * 8 + i;
        float pe = acc[i][0]*a0 + acc[i][1]*a1 + acc[i][2]*a2 + acc[i][3]*a3;
        float pr = acc[i][0]*r0 + acc[i][1]*r1 + acc[i][2]*r2 + acc[i][3]*r3;
        float pq = acc[i][0]*w0 + acc[i][1]*w1 + acc[i][2]*w2 + acc[i][3]*w3;
#pragma unroll
        for (int o = 1; o < 8; o <<= 1) {
            pe += __shfl_xor(pe, o); pr += __shfl_xor(pr, o); pq += __shfl_xor(pq, o);
        }
        if ((tc & 7) == 0 && gr < M) {
            el[gr * 4 + head] = pe; er[gr * 4 + head] = pr;
            if (Wc) q4[gr * 4 + head] = pq;
        }
    }
}

// ---------- MERGED: gemm0 || degree count (+rank) || b0.Wc0 prep ----------
// R8 post-mortem: k_deg (atomic-latency-bound, VALU 0.4%) and k_gemm0
// (VALU-bound, 39%) are independent and complementary -> co-schedule in one
// launch (m114: MFMA/VALU/memory pipes overlap across waves). Degree atomics
// return the within-node rank so the CSR scatter needs NO atomics.
#define G0B 782            // 2 x 391 gemm blocks
__global__ __launch_bounds__(256) void k_g0deg(P p) {
    int blk = blockIdx.x;
    if (blk < G0B) {
        gemm_body(p.feature, p.W0, p.z0, NN, FIN, p.al0, p.ar0, p.el0, p.er0,
                  p.Wc0, p.q4, blk & 1, blk >> 1);
    } else if (blk < G0B + 3125) {
        int e = (blk - G0B) * 256 + threadIdx.x;
        if (e < EE) {
            p.rank[e] = atomicAdd(&p.deg_i[p.dst[e]], 1);
            atomicAdd(&p.deg_o[p.src[e]], 1);
        }
    } else {
        int l = threadIdx.x;
        if (l < 64) {
            float t = p.b0[l] * p.Wc0[l] + p.b0[l + 64] * p.Wc0[l + 64];
#pragma unroll
            for (int o = 1; o < 64; o <<= 1) t += __shfl_xor(t, o);
            if (l == 0) p.b0wc[0] = t;
        }
    }
}

// ---------- MERGED: gemm1 || layer-1 degree (+rank) ----------
#define G1B 392            // 2 x 196 gemm blocks
__global__ __launch_bounds__(256) void k_g1deg(P p) {
    int blk = blockIdx.x;
    if (blk < G1B) {
        gemm_body(p.xk, p.W1, p.z1, KK, HD, p.al1, p.ar1, p.el1, p.er1,
                  nullptr, nullptr, blk & 1, blk >> 1);
    } else {
        int e = (blk - G1B) * 256 + threadIdx.x;
        if (e < EE) {
            int ds = p.slot[p.src[e]], dd = p.slot[p.dst[e]];
            int r = -1;
            if (ds >= 0 && dd >= 0) r = atomicAdd(&p.deg1[dd], 1);
            p.rank[e] = r;
        }
    }
}

// ---------- two-level exclusive scan ----------
__global__ __launch_bounds__(256) void k_bsum(const int* __restrict__ deg,
                                              int* __restrict__ bsum, int n) {
    int i = blockIdx.x * 256 + threadIdx.x;
    int v = (i < n) ? deg[i] : 0;
    int lane = threadIdx.x & 63, w = threadIdx.x >> 6;
    __shared__ int ws[4];
#pragma unroll
    for (int o = 1; o < 64; o <<= 1) v += __shfl_xor(v, o);
    if (lane == 0) ws[w] = v;
    __syncthreads();
    if (threadIdx.x == 0) bsum[blockIdx.x] = ws[0] + ws[1] + ws[2] + ws[3];
}
__global__ __launch_bounds__(256) void k_bscan(const int* __restrict__ bsum, int nb,
                                               int* __restrict__ boff,
                                               int* __restrict__ off, int n) {
    __shared__ int ws[4];
    __shared__ int wo[5];
    int t = threadIdx.x;
    int v = (t < nb) ? bsum[t] : 0;
    int lane = t & 63, w = t >> 6;
    int incl = v;
    for (int o = 1; o < 64; o <<= 1) { int u = __shfl_up(incl, o); if (lane >= o) incl += u; }
    if (lane == 63) ws[w] = incl;
    __syncthreads();
    if (t == 0) { int a = 0; for (int i = 0; i < 4; i++) { wo[i] = a; a += ws[i]; } wo[4] = a; }
    __syncthreads();
    if (t < nb) boff[t] = wo[w] + incl - v;
    if (t == 0) off[n] = wo[4];
}
__global__ __launch_bounds__(256) void k_fscan(const int* __restrict__ deg,
                                               const int* __restrict__ boff,
                                               int* __restrict__ off, int n) {
    __shared__ int ws[4];
    __shared__ int wo[4];
    int i = blockIdx.x * 256 + threadIdx.x;
    int v = (i < n) ? deg[i] : 0;
    int lane = threadIdx.x & 63, w = threadIdx.x >> 6;
    int incl = v;
    for (int o = 1; o < 64; o <<= 1) { int u = __shfl_up(incl, o); if (lane >= o) incl += u; }
    if (lane == 63) ws[w] = incl;
    __syncthreads();
    if (threadIdx.x == 0) { int a = 0; for (int k = 0; k < 4; k++) { wo[k] = a; a += ws[k]; } }
    __syncthreads();
    if (i < n) off[i] = boff[blockIdx.x] + wo[w] + incl - v;
}

// ---------- CSR scatters: atomic-free (rank precomputed in deg pass) ----------
__global__ void k_scatter0(P p) {
    int e = blockIdx.x * blockDim.x + threadIdx.x;
    if (e >= EE) return;
    p.csr_src[p.off0[p.dst[e]] + p.rank[e]] = p.src[e];
}
__global__ void k_scatter1(P p) {
    int e = blockIdx.x * blockDim.x + threadIdx.x;
    if (e >= EE) return;
    int r = p.rank[e];
    if (r >= 0) {
        int dd = p.slot[p.dst[e]];
        p.csr_src[p.off1[dd] + r] = p.slot[p.src[e]];
    }
}

// ---------- layer-0 softmax + SCALAR q-gather (all nodes) ----------
__global__ __launch_bounds__(256) void k_fgatlite(
    const int* __restrict__ off, const int* __restrict__ csrs,
    const float* __restrict__ el, const float* __restrict__ er,
    const float* __restrict__ q4, const int* __restrict__ dego,
    const float* __restrict__ b0wc,
    float* __restrict__ hc, float* __restrict__ m0f, float* __restrict__ s0f) {
    int wv = threadIdx.x >> 6, lane = threadIdx.x & 63;
    int v = blockIdx.x * 4 + wv;
    int b = off[v], e = off[v + 1], deg = e - b;
    int h = lane >> 4, sub = lane & 15;
    float erh = er[(size_t)v * 4 + h];
    float m = NEGF;
    for (int li = sub; li < deg; li += 16) {
        int s = csrs[b + li];
        m = fmaxf(m, lrelu(el[(size_t)s * 4 + h] + erh));
    }
#pragma unroll
    for (int o = 1; o < 16; o <<= 1) m = fmaxf(m, __shfl_xor(m, o));
    float ssum = 0.f, hq = 0.f;
    for (int li = sub; li < deg; li += 16) {
        int s = csrs[b + li];
        float ex = expf(lrelu(el[(size_t)s * 4 + h] + erh) - m);
        ssum += ex;
        hq = fmaf(ex, q4[(size_t)s * 4 + h], hq);
    }
#pragma unroll
    for (int o = 1; o < 16; o <<= 1) { ssum += __shfl_xor(ssum, o); hq += __shfl_xor(hq, o); }
    if (sub == 0) { m0f[v * 4 + h] = m; s0f[v * 4 + h] = ssum; }
    float t = hq / fmaxf(ssum, 1e-16f);     // uniform within head group
    t += __shfl_xor(t, 16);
    t += __shfl_xor(t, 32);                 // sum over 4 heads
    if (lane == 0)
        hc[v] = (t + b0wc[0]) / sqrtf(fmaxf((float)dego[v], 1.f));
}

// ---------- full x for SELECTED nodes only ----------
__global__ __launch_bounds__(256) void k_fgatx(
    const int* __restrict__ list, const float* __restrict__ tscale,
    const int* __restrict__ off, const int* __restrict__ csrs,
    const float* __restrict__ el, const float* __restrict__ er,
    const float* __restrict__ m0f, const float* __restrict__ s0f,
    const float* __restrict__ z, const float* __restrict__ b0,
    float* __restrict__ xk) {
    __shared__ int ssrc[4][CW];
    __shared__ float sexp[4][CW][4];
    int wv = threadIdx.x >> 6, lane = threadIdx.x & 63;
    int i = blockIdx.x * 4 + wv;
    int v = list[i];
    int b = off[v], e = off[v + 1], deg = e - b;
    int h = lane >> 4, sub = lane & 15;
    float erh = er[(size_t)v * 4 + h];
    float mh = m0f[v * 4 + h];
    for (int li = sub; li < deg; li += 16) {
        int s = csrs[b + li];
        if (h == 0 && li < CW) ssrc[wv][li] = s;
        if (li < CW) sexp[wv][li][h] = expf(lrelu(el[(size_t)s * 4 + h] + erh) - mh);
    }
    __syncthreads();
    int h0 = lane >> 5, h1 = h0 + 2;
    float s0 = s0f[v * 4 + h0], s1 = s0f[v * 4 + h1];
    float m0 = m0f[v * 4 + h0], m1 = m0f[v * 4 + h1];
    float er0v = er[(size_t)v * 4 + h0], er1v = er[(size_t)v * 4 + h1];
    int c0 = lane, c1 = lane + 64;
    float acc0 = 0.f, acc1 = 0.f;
    for (int li = 0; li < deg; li++) {
        int s; float w0, w1;
        if (li < CW) {
            s = ssrc[wv][li];
            w0 = sexp[wv][li][h0]; w1 = sexp[wv][li][h1];
        } else {
            s = csrs[b + li];
            w0 = expf(lrelu(el[(size_t)s * 4 + h0] + er0v) - m0);
            w1 = expf(lrelu(el[(size_t)s * 4 + h1] + er1v) - m1);
        }
        int su = __builtin_amdgcn_readfirstlane(s);
        const float* zr = z + (size_t)su * HD;
        acc0 = fmaf(w0, zr[c0], acc0);
        acc1 = fmaf(w1, zr[c1], acc1);
    }
    float ts = tscale[i];
    float* xr = xk + (size_t)i * HD;
    xr[c0] = (acc0 / fmaxf(s0, 1e-16f) + b0[c0]) * ts;
    xr[c1] = (acc1 / fmaxf(s1, 1e-16f) + b0[c1]) * ts;
}

// ---------- SAGPool score ----------
__global__ void k_score(P p) {
    int v = blockIdx.x * blockDim.x + threadIdx.x;
    if (v >= NN) return;
    int b = p.off0[v], en = p.off0[v + 1];
    float acc = 0.f;
    for (int i = b; i < en; i++) acc += p.hc[p.csr_src[i]];
    float dg = fmaxf((float)(en - b), 1.f);
    float sc = acc / sqrtf(dg) + p.bc0[0];
    p.score[v] = sc;
    p.keys[v] = fkey(sc);
}

// ---------- radix select: 2 x 16-bit passes ----------
__global__ void k_hist2(P p, int level) {
    int v = blockIdx.x * blockDim.x + threadIdx.x;
    if (v >= NN) return;
    unsigned key = p.keys[v];
    if (level == 0) atomicAdd(&p.binsHi[key >> 16], 1u);
    else if ((key >> 16) == p.rs[2]) atomicAdd(&p.binsLo[key & 0xFFFFu], 1u);
}
__global__ __launch_bounds__(1024) void k_rsel2(P p, int level) {
    const unsigned* bins = level ? p.binsLo : p.binsHi;
    int K = level ? (int)p.rs[3] : KK;
    __shared__ unsigned wsm[16];
    __shared__ unsigned wpre[17];
    int t = threadIdx.x;
    unsigned base = (unsigned)t * 64;
    const uint4* b4 = (const uint4*)(bins + base);
    unsigned S = 0;
#pragma unroll
    for (int i = 0; i < 16; i++) {
        uint4 u = b4[i];
        S += u.x + u.y + u.z + u.w;
    }
    int lane = t & 63, w = t >> 6;
    unsigned val = S;
    for (int o = 1; o < 64; o <<= 1) { unsigned u = __shfl_up(val, o); if (lane >= o) val += u; }
    if (lane == 63) wsm[w] = val;
    __syncthreads();
    if (t == 0) { unsigned a = 0; for (int i = 0; i < 16; i++) { wpre[i] = a; a += wsm[i]; } wpre[16] = a; }
    __syncthreads();
    unsigned incl = wpre[w] + val;
    unsigned running = wpre[16] - incl;    // keys in strictly higher bins
    for (int i = 63; i >= 0; i--) {
        unsigned c = bins[base + i];
        unsigned above = running;
        running += c;
        if ((int)above < K && (int)running >= K) {
            if (level == 0) { p.rs[2] = base + (unsigned)i; p.rs[3] = (unsigned)(K - (int)above); }
            else { p.rs[0] = (p.rs[2] << 16) | (base + (unsigned)i); p.rs[1] = (unsigned)(K - (int)above); }
        }
    }
}
__global__ void k_sel(P p) {
    int v = blockIdx.x * blockDim.x + threadIdx.x;
    if (v >= NN) return;
    p.sel[v] = (p.keys[v] > p.rs[0]) ? 1 : 0;
}
__global__ __launch_bounds__(1024) void k_ties(P p) {   // lowest-index ties (matches top_k)
    __shared__ int base;
    __shared__ int wsums[16];
    unsigned pivot = p.rs[0];
    int need = (int)p.rs[1];
    if (threadIdx.x == 0) base = 0;
    __syncthreads();
    for (int st = 0; st < NN; st += 1024) {
        int v = st + (int)threadIdx.x;
        int flag = (v < NN && p.keys[v] == pivot) ? 1 : 0;
        unsigned long long m = __ballot(flag);
        int lane = threadIdx.x & 63, w = threadIdx.x >> 6;
        int pre = __popcll(m & ((1ull << lane) - 1ull));
        if (lane == 0) wsums[w] = __popcll(m);
        __syncthreads();
        int woff = 0;
        for (int i = 0; i < w; i++) woff += wsums[i];
        int rank = base + woff + pre;
        if (flag && rank < need) p.sel[v] = 1;
        __syncthreads();
        if (threadIdx.x == 0) {
            int s = 0;
            for (int i = 0; i < 16; i++) s += wsums[i];
            base += s;
        }
        __syncthreads();
    }
}
__global__ void k_list(P p) {
    int v = blockIdx.x * blockDim.x + threadIdx.x;
    if (v >= NN) return;
    if (p.sel[v]) {
        int i = atomicAdd(p.cnt, 1);
        p.list[i] = v;
        p.slot[v] = i;
        p.tscale[i] = tanhf(p.score[v]);
    } else {
        p.slot[v] = -1;
    }
}

// ---------- layer-1 fused GAT (wave-per-node) + res/g epilogue ----------
__global__ __launch_bounds__(256) void k_fgat2(
    const int* __restrict__ off, const int* __restrict__ csrs,
    const float* __restrict__ el, const float* __restrict__ er,
    const float* __restrict__ z, const float* __restrict__ bias,
    float* __restrict__ mf, float* __restrict__ sf,
    const float* __restrict__ gW, const float* __restrict__ gb,
    float* __restrict__ res, float* __restrict__ g) {
    __shared__ int ssrc[4][CW];
    __shared__ float sexp[4][CW][4];
    int wv = threadIdx.x >> 6, lane = threadIdx.x & 63;
    int v = blockIdx.x * 4 + wv;
    int b = off[v], e = off[v + 1], deg = e - b;
    int h = lane >> 4, sub = lane & 15;
    float4 er4 = *(const float4*)(er + (size_t)v * 4);
    float erh = ((const float*)&er4)[h];
    float m = NEGF;
    for (int li = sub; li < deg; li += 16) {
        int s = csrs[b + li];
        if (h == 0 && li < CW) ssrc[wv][li] = s;
        m = fmaxf(m, lrelu(el[(size_t)s * 4 + h] + erh));
    }
#pragma unroll
    for (int o = 1; o < 16; o <<= 1) m = fmaxf(m, __shfl_xor(m, o));
    float ssum = 0.f;
    for (int li = sub; li < deg; li += 16) {
        int s = csrs[b + li];
        float x = expf(lrelu(el[(size_t)s * 4 + h] + erh) - m);
        if (li < CW) sexp[wv][li][h] = x;
        ssum += x;
    }
#pragma unroll
    for (int o = 1; o < 16; o <<= 1) ssum += __shfl_xor(ssum, o);
    if (sub == 0) { mf[v * 4 + h] = m; sf[v * 4 + h] = ssum; }
    __syncthreads();
    int h0 = lane >> 5, h1 = h0 + 2;
    float m0 = __shfl(m, h0 << 4), m1 = __shfl(m, h1 << 4);
    float s0 = __shfl(ssum, h0 << 4), s1 = __shfl(ssum, h1 << 4);
    int c0 = lane, c1 = lane + 64;
    float acc0 = 0.f, acc1 = 0.f;
    for (int li = 0; li < deg; li++) {
        int s; float w0, w1;
        if (li < CW) {
            s = ssrc[wv][li];
            w0 = sexp[wv][li][h0]; w1 = sexp[wv][li][h1];
        } else {
            s = csrs[b + li];
            w0 = expf(lrelu(el[(size_t)s * 4 + h0] + ((const float*)&er4)[h0]) - m0);
            w1 = expf(lrelu(el[(size_t)s * 4 + h1] + ((const float*)&er4)[h1]) - m1);
        }
        int su = __builtin_amdgcn_readfirstlane(s);
        const float* zr = z + (size_t)su * HD;
        acc0 = fmaf(w0, zr[c0], acc0);
        acc1 = fmaf(w1, zr[c1], acc1);
    }
    float xc0 = acc0 / fmaxf(s0, 1e-16f) + bias[c0];
    float xc1 = acc1 / fmaxf(s1, 1e-16f) + bias[c1];
    float t = xc0 + xc1;              // x[c]+x[c+64]
    t += __shfl_xor(t, 32);           // + x[c+32]+x[c+96]
    float pg = 0.f;
    if (lane < 32) {
        float r = 0.25f * t;
        res[(size_t)v * 32 + lane] = r;
        pg = r * gW[lane];
    }
#pragma unroll
    for (int o = 1; o < 32; o <<= 1) pg += __shfl_xor(pg, o);
    if (lane == 0) g[v] = pg + gb[0];
}

// per-edge alpha outputs: pure reads, writes atten+strength for ALL edges
__global__ void k_ealpha1(P p) {
    int e = blockIdx.x * blockDim.x + threadIdx.x;
    if (e >= EE) return;
    int ds = p.slot[p.src[e]], dd = p.slot[p.dst[e]];
    float a[4] = {0.f, 0.f, 0.f, 0.f};
    float st = 0.f;
    if (ds >= 0 && dd >= 0) {
        float4 es = *(const float4*)(p.el1 + ds * 4);
        float4 ed = *(const float4*)(p.er1 + dd * 4);
        float l[4] = {lrelu(es.x + ed.x), lrelu(es.y + ed.y), lrelu(es.z + ed.z), lrelu(es.w + ed.w)};
#pragma unroll
        for (int h = 0; h < 4; h++) {
            float m = p.m1f[dd * 4 + h];
            float ex = expf(l[h] - m);
            a[h] = ex / fmaxf(p.s1f[dd * 4 + h], 1e-16f);
        }
        st = p.strength[e];
    }
    float* o = p.out + ATT_OFF + (size_t)e * 4;
    *(float2*)(o) = make_float2(a[0], a[1]);
    *(float2*)(o + 2) = make_float2(a[2], a[3]);
    p.out[STR_OFF + e] = st;
}

// ---------- readout ----------
__global__ void k_gmax(P p) {
    __shared__ float red[256];
    int t = threadIdx.x;
    float m = -3.4e38f;
    for (int i = blockIdx.x * 256 + t; i < KK; i += gridDim.x * 256) m = fmaxf(m, p.g[i]);
    red[t] = m;
    __syncthreads();
    for (int o = 128; o > 0; o >>= 1) { if (t < o) red[t] = fmaxf(red[t], red[t + o]); __syncthreads(); }
    if (t == 0) atomicMax(p.gmaxk, fkey(red[0]));   // memset-0 identity ok
}
#define WSUM_BLOCKS 104
__global__ __launch_bounds__(256) void k_wsum(P p) {
    __shared__ double vred[256];
    __shared__ double zred[8];
    int t = threadIdx.x, il = t >> 5, d = t & 31;
    float gm = unfkey(*p.gmaxk);
    double accv = 0.0, accw = 0.0;
    for (int i = blockIdx.x * 8 + il; i < KK; i += WSUM_BLOCKS * 8) {
        float w = expf(p.g[i] - gm);
        accv += (double)(w * p.res[(size_t)i * 32 + d]);
        if (d == 0) accw += (double)w;
    }
    vred[t] = accv;
    if (d == 0) zred[il] = accw;
    __syncthreads();
    if (il == 0) {
        double s = 0;
#pragma unroll
        for (int k2 = 0; k2 < 8; k2++) s += vred[k2 * 32 + d];
        atomicAdd(&p.racc[d], s);
    }
    if (t == 32) {
        double z2 = 0;
#pragma unroll
        for (int k2 = 0; k2 < 8; k2++) z2 += zred[k2];
        atomicAdd(p.Zacc, z2);
    }
}
__global__ void k_final(P p) {
    __shared__ float rb[32];
    int t = threadIdx.x;
    double Z = *p.Zacc;
    if (t < 32) {
        float r = (float)(p.racc[t] / Z);
        p.out[t] = r;
        rb[t] = r;
    }
    __syncthreads();
    if (t < 2) {
        float s = 0.f;
        for (int d = 0; d < 32; d++) s += rb[d] * p.cW[d * 2 + t];
        p.out[32 + t] = s + p.cb[t];
    }
}

// ---------- host ----------
extern "C" void kernel_launch(void* const* d_in, const int* in_sizes, int n_in,
                              void* d_out, int out_size, void* d_ws, size_t ws_size,
                              hipStream_t stream) {
    (void)in_sizes; (void)n_in; (void)out_size; (void)ws_size;
    P p;
    p.feature  = (const float*)d_in[0];
    p.strength = (const float*)d_in[1];
    p.W0  = (const float*)d_in[2];  p.b0  = (const float*)d_in[3];
    p.al0 = (const float*)d_in[4];  p.ar0 = (const float*)d_in[5];
    p.Wc0 = (const float*)d_in[6];  p.bc0 = (const float*)d_in[7];
    p.W1  = (const float*)d_in[8];  p.b1  = (const float*)d_in[9];
    p.al1 = (const float*)d_in[10]; p.ar1 = (const float*)d_in[11];
    p.gW  = (const float*)d_in[12]; p.gb  = (const float*)d_in[13];
    p.cW  = (const float*)d_in[14]; p.cb  = (const float*)d_in[15];
    p.src = (const int*)d_in[16];   p.dst = (const int*)d_in[17];
    p.out = (float*)d_out;

    char* ws = (char*)d_ws;
    size_t off = 0;
    auto alloc = [&](size_t bytes) -> void* {
        void* r = ws + off;
        off = (off + bytes + 255) & ~(size_t)255;
        return r;
    };
    // ---- zeroed region (must stay first/contiguous) ----
    p.Zacc  = (double*)alloc(8);
    p.racc  = (double*)alloc(32 * 8);
    p.deg_i = (int*)alloc((size_t)NN * 4);
    p.deg_o = (int*)alloc((size_t)NN * 4);
    p.deg1  = (int*)alloc((size_t)KK * 4);
    p.cnt   = (int*)alloc(4);
    p.gmaxk = (unsigned*)alloc(4);
    p.rs    = (unsigned*)alloc(16);
    p.binsHi = (unsigned*)alloc(65536 * 4);
    p.binsLo = (unsigned*)alloc(65536 * 4);
    size_t zbytes = off;
    // ---- big buffers ----
    p.z0 = (float*)alloc((size_t)NN * HD * 4);
    p.xk = (float*)alloc((size_t)KK * HD * 4);
    p.z1 = (float*)alloc((size_t)KK * HD * 4);
    p.csr_src = (int*)alloc((size_t)EE * 4);
    p.rank    = (int*)alloc((size_t)EE * 4);
    p.el0 = (float*)alloc((size_t)NN * 4 * 4);
    p.er0 = (float*)alloc((size_t)NN * 4 * 4);
    p.q4  = (float*)alloc((size_t)NN * 4 * 4);
    p.m0f = (float*)alloc((size_t)NN * 4 * 4);
    p.s0f = (float*)alloc((size_t)NN * 4 * 4);
    p.b0wc = (float*)alloc(4);
    p.off0 = (int*)alloc((size_t)(NN + 1) * 4);
    p.off1 = (int*)alloc((size_t)(KK + 1) * 4);
    p.bsum = (int*)alloc(256 * 4);
    p.boff = (int*)alloc(256 * 4);
    p.hc    = (float*)alloc((size_t)NN * 4);
    p.score = (float*)alloc((size_t)NN * 4);
    p.keys  = (unsigned*)alloc((size_t)NN * 4);
    p.sel   = (int*)alloc((size_t)NN * 4);
    p.slot  = (int*)alloc((size_t)NN * 4);
    p.list  = (int*)alloc((size_t)KK * 4);
    p.tscale = (float*)alloc((size_t)KK * 4);
    p.el1 = (float*)alloc((size_t)KK * 4 * 4);
    p.er1 = (float*)alloc((size_t)KK * 4 * 4);
    p.m1f = (float*)alloc((size_t)KK * 4 * 4);
    p.s1f = (float*)alloc((size_t)KK * 4 * 4);
    p.res = (float*)alloc((size_t)KK * DD * 4);
    p.g   = (float*)alloc((size_t)KK * 4);

    const int GB_E = (EE + 255) / 256;        // 3125
    const int GB_N = (NN + 255) / 256;        // 196
    const int GB_K = (KK + 255) / 256;        // 98

    hipMemsetAsync(d_ws, 0, zbytes, stream);

    // ---- GAT layer 0 (gemm0 || deg || prep in one launch) ----
    k_g0deg<<<G0B + GB_E + 1, 256, 0, stream>>>(p);
    k_bsum<<<GB_N, 256, 0, stream>>>(p.deg_i, p.bsum, NN);
    k_bscan<<<1, 256, 0, stream>>>(p.bsum, GB_N, p.boff, p.off0, NN);
    k_fscan<<<GB_N, 256, 0, stream>>>(p.deg_i, p.boff, p.off0, NN);
    k_scatter0<<<GB_E, 256, 0, stream>>>(p);
    k_fgatlite<<<NN / 4, 256, 0, stream>>>(p.off0, p.csr_src, p.el0, p.er0, p.q4,
                                           p.deg_o, p.b0wc, p.hc, p.m0f, p.s0f);

    // ---- SAGPool ----
    k_score<<<GB_N, 256, 0, stream>>>(p);
    k_hist2<<<GB_N, 256, 0, stream>>>(p, 0);
    k_rsel2<<<1, 1024, 0, stream>>>(p, 0);
    k_hist2<<<GB_N, 256, 0, stream>>>(p, 1);
    k_rsel2<<<1, 1024, 0, stream>>>(p, 1);
    k_sel<<<GB_N, 256, 0, stream>>>(p);
    k_ties<<<1, 1024, 0, stream>>>(p);
    k_list<<<GB_N, 256, 0, stream>>>(p);
    k_fgatx<<<KK / 4, 256, 0, stream>>>(p.list, p.tscale, p.off0, p.csr_src,
                                        p.el0, p.er0, p.m0f, p.s0f, p.z0, p.b0, p.xk);

    // ---- GAT layer 1 (gemm1 || deg1 in one launch) ----
    k_g1deg<<<G1B + GB_E, 256, 0, stream>>>(p);
    k_bsum<<<GB_K, 256, 0, stream>>>(p.deg1, p.bsum, KK);
    k_bscan<<<1, 256, 0, stream>>>(p.bsum, GB_K, p.boff, p.off1, KK);
    k_fscan<<<GB_K, 256, 0, stream>>>(p.deg1, p.boff, p.off1, KK);
    k_scatter1<<<GB_E, 256, 0, stream>>>(p);
    k_fgat2<<<KK / 4, 256, 0, stream>>>(p.off1, p.csr_src, p.el1, p.er1, p.z1, p.b1,
                                        p.m1f, p.s1f, p.gW, p.gb, p.res, p.g);
    k_ealpha1<<<GB_E, 256, 0, stream>>>(p);

    // ---- readout ----
    k_gmax<<<98, 256, 0, stream>>>(p);
    k_wsum<<<WSUM_BLOCKS, 256, 0, stream>>>(p);
    k_final<<<1, 64, 0, stream>>>(p);
}